// Round 1
// baseline (1414.325 us; speedup 1.0000x reference)
//
#include <hip/hip_runtime.h>
#include <math.h>

#define NPT 4096
#define DIM 256
#define NVAR 9
#define INV_TEMP 20.0f
#define THR 0.01f
#define EPSD 1e-12f

// ---------- helpers: order-preserving float<->uint for atomicMax on floats ----------
__device__ __forceinline__ unsigned frep(float x) {
    unsigned u = __float_as_uint(x);
    return (u & 0x80000000u) ? ~u : (u | 0x80000000u);
}
__device__ __forceinline__ float funrep(unsigned u) {
    return __uint_as_float((u & 0x80000000u) ? (u ^ 0x80000000u) : ~u);
}

// ---------- steering: C_k[n,e] = sum_d A[n,d] * M_k[e,d]  (NT GEMM) ----------
// grid (64, 4, 8), 256 threads, 64x64 tile, 4x4 microtile
__global__ __launch_bounds__(256) void steer_kernel(const float* __restrict__ A,
                                                    const float* __restrict__ protos,
                                                    float* __restrict__ out) {
    __shared__ float As[16][64];
    __shared__ float Bs[16][64];
    const int k = blockIdx.z;
    const float* B = protos + (size_t)k * DIM * DIM;
    float* C = out + (size_t)k * NPT * DIM;
    const int tid = threadIdx.x;
    const int rb = blockIdx.x * 64, cb = blockIdx.y * 64;
    const int li = tid >> 2, lk = (tid & 3) << 2;
    const int tr = (tid >> 4) << 2, tc = (tid & 15) << 2;
    float acc[4][4] = {};
    for (int k0 = 0; k0 < DIM; k0 += 16) {
        float4 av = *(const float4*)&A[(size_t)(rb + li) * DIM + k0 + lk];
        float4 bv = *(const float4*)&B[(size_t)(cb + li) * DIM + k0 + lk];
        __syncthreads();
        As[lk + 0][li] = av.x; As[lk + 1][li] = av.y; As[lk + 2][li] = av.z; As[lk + 3][li] = av.w;
        Bs[lk + 0][li] = bv.x; Bs[lk + 1][li] = bv.y; Bs[lk + 2][li] = bv.z; Bs[lk + 3][li] = bv.w;
        __syncthreads();
#pragma unroll
        for (int kk = 0; kk < 16; ++kk) {
            float4 a = *(const float4*)&As[kk][tr];
            float4 b = *(const float4*)&Bs[kk][tc];
            const float* ap = (const float*)&a;
            const float* bp = (const float*)&b;
#pragma unroll
            for (int i = 0; i < 4; ++i)
#pragma unroll
                for (int j = 0; j < 4; ++j)
                    acc[i][j] = fmaf(ap[i], bp[j], acc[i][j]);
        }
    }
#pragma unroll
    for (int i = 0; i < 4; ++i) {
        float4 v = make_float4(acc[i][0], acc[i][1], acc[i][2], acc[i][3]);
        *(float4*)&C[(size_t)(rb + tr + i) * DIM + cb + tc] = v;
    }
}

// ---------- row squared norms: one wave (64 lanes) per row of 256 floats ----------
__global__ __launch_bounds__(256) void rownorm_kernel(const float* __restrict__ X,
                                                      float* __restrict__ out, int nrows) {
    int w = blockIdx.x * 4 + (threadIdx.x >> 6);
    int lane = threadIdx.x & 63;
    if (w >= nrows) return;
    float4 v = *(const float4*)&X[(size_t)w * DIM + lane * 4];
    float s = v.x * v.x + v.y * v.y + v.z * v.z + v.w * v.w;
#pragma unroll
    for (int o = 32; o; o >>= 1) s += __shfl_xor(s, o);
    if (lane == 0) out[w] = s;
}

// ---------- main fused corr: c = -20*sqrt(min_k d2_k + eps), track row/col max ----------
// grid (64, 64), 256 threads, 64x64 tile, 4x4 microtile, 9 variants sequentially
__global__ __launch_bounds__(256) void corr_kernel(const float* __restrict__ dA,
                                                   const float* __restrict__ steered,
                                                   const float* __restrict__ dB,
                                                   const float* __restrict__ a2,
                                                   const float* __restrict__ b2,
                                                   float* __restrict__ cOut,
                                                   unsigned* __restrict__ rm_rep,
                                                   unsigned* __restrict__ cm_rep) {
    __shared__ float As[16][64];
    __shared__ float Bs[16][64];
    __shared__ unsigned redR[64];
    __shared__ unsigned redC[64];
    const int tid = threadIdx.x;
    const int rb = blockIdx.x * 64, cb = blockIdx.y * 64;
    const int li = tid >> 2, lk = (tid & 3) << 2;
    const int tr = (tid >> 4) << 2, tc = (tid & 15) << 2;

    float b2v[4];
#pragma unroll
    for (int j = 0; j < 4; ++j) b2v[j] = b2[cb + tc + j];

    float zmin[4][4];
#pragma unroll
    for (int i = 0; i < 4; ++i)
#pragma unroll
        for (int j = 0; j < 4; ++j) zmin[i][j] = 3.402823466e38f;

    for (int v = 0; v < NVAR; ++v) {
        const float* Av = (v == 0) ? dA : steered + (size_t)(v - 1) * NPT * DIM;
        float acc[4][4] = {};
        for (int k0 = 0; k0 < DIM; k0 += 16) {
            float4 av = *(const float4*)&Av[(size_t)(rb + li) * DIM + k0 + lk];
            float4 bv = *(const float4*)&dB[(size_t)(cb + li) * DIM + k0 + lk];
            __syncthreads();
            As[lk + 0][li] = av.x; As[lk + 1][li] = av.y; As[lk + 2][li] = av.z; As[lk + 3][li] = av.w;
            Bs[lk + 0][li] = bv.x; Bs[lk + 1][li] = bv.y; Bs[lk + 2][li] = bv.z; Bs[lk + 3][li] = bv.w;
            __syncthreads();
#pragma unroll
            for (int kk = 0; kk < 16; ++kk) {
                float4 a = *(const float4*)&As[kk][tr];
                float4 b = *(const float4*)&Bs[kk][tc];
                const float* ap = (const float*)&a;
                const float* bp = (const float*)&b;
#pragma unroll
                for (int i = 0; i < 4; ++i)
#pragma unroll
                    for (int j = 0; j < 4; ++j)
                        acc[i][j] = fmaf(ap[i], bp[j], acc[i][j]);
            }
        }
        float a2r[4];
#pragma unroll
        for (int i = 0; i < 4; ++i) a2r[i] = a2[v * NPT + rb + tr + i];
#pragma unroll
        for (int i = 0; i < 4; ++i)
#pragma unroll
            for (int j = 0; j < 4; ++j) {
                float d2 = fmaxf(a2r[i] + b2v[j] - 2.0f * acc[i][j], 0.0f);
                zmin[i][j] = fminf(zmin[i][j], d2);
            }
    }

    if (tid < 64) { redR[tid] = 0u; redC[tid] = 0u; }
    __syncthreads();

    float cvals[4][4];
#pragma unroll
    for (int i = 0; i < 4; ++i) {
#pragma unroll
        for (int j = 0; j < 4; ++j)
            cvals[i][j] = -INV_TEMP * sqrtf(zmin[i][j] + EPSD);
        float4 v = make_float4(cvals[i][0], cvals[i][1], cvals[i][2], cvals[i][3]);
        *(float4*)&cOut[(size_t)(rb + tr + i) * NPT + cb + tc] = v;
        float rmax = fmaxf(fmaxf(cvals[i][0], cvals[i][1]), fmaxf(cvals[i][2], cvals[i][3]));
        atomicMax(&redR[tr + i], frep(rmax));
    }
#pragma unroll
    for (int j = 0; j < 4; ++j) {
        float cmax = fmaxf(fmaxf(cvals[0][j], cvals[1][j]), fmaxf(cvals[2][j], cvals[3][j]));
        atomicMax(&redC[tc + j], frep(cmax));
    }
    __syncthreads();
    if (tid < 64) {
        atomicMax(&rm_rep[rb + tid], redR[tid]);
        atomicMax(&cm_rep[cb + tid], redC[tid]);
    }
}

// ---------- row softmax denominators: one block per row ----------
__global__ __launch_bounds__(256) void rowsum_kernel(const float* __restrict__ C,
                                                     const unsigned* __restrict__ rm_rep,
                                                     float* __restrict__ rowsum) {
    int n = blockIdx.x;
    float rm = funrep(rm_rep[n]);
    const float4* row = (const float4*)(C + (size_t)n * NPT);
    float s = 0.f;
#pragma unroll
    for (int it = 0; it < 4; ++it) {
        float4 v = row[it * 256 + threadIdx.x];
        s += expf(v.x - rm) + expf(v.y - rm) + expf(v.z - rm) + expf(v.w - rm);
    }
#pragma unroll
    for (int o = 32; o; o >>= 1) s += __shfl_xor(s, o);
    __shared__ float ws4[4];
    if ((threadIdx.x & 63) == 0) ws4[threadIdx.x >> 6] = s;
    __syncthreads();
    if (threadIdx.x == 0) rowsum[n] = (ws4[0] + ws4[1]) + (ws4[2] + ws4[3]);
}

// ---------- col softmax denominators: strip kernel, grid (64,16) ----------
__global__ __launch_bounds__(256) void colsum_kernel(const float* __restrict__ C,
                                                     const unsigned* __restrict__ cm_rep,
                                                     float* __restrict__ colsum) {
    int col = blockIdx.x * 64 + (threadIdx.x & 63);
    int rl = threadIdx.x >> 6;
    int r0 = blockIdx.y * 256;
    float cm = funrep(cm_rep[col]);
    float s = 0.f;
    for (int it = 0; it < 64; ++it) {
        int r = r0 + it * 4 + rl;
        s += expf(C[(size_t)r * NPT + col] - cm);
    }
    __shared__ float red[256];
    red[threadIdx.x] = s;
    __syncthreads();
    if (threadIdx.x < 64)
        atomicAdd(&colsum[col], (red[threadIdx.x] + red[threadIdx.x + 64]) +
                                (red[threadIdx.x + 128] + red[threadIdx.x + 192]));
}

// ---------- P = colsoftmax * rowsoftmax (in place), track row/col max of P ----------
__global__ __launch_bounds__(256) void p_kernel(float* __restrict__ C,
                                                const unsigned* __restrict__ rm_rep,
                                                const unsigned* __restrict__ cm_rep,
                                                const float* __restrict__ rowsum,
                                                const float* __restrict__ colsum,
                                                unsigned* __restrict__ rmp_rep,
                                                unsigned* __restrict__ cmp_rep) {
    int lane = threadIdx.x & 63;
    int col = blockIdx.x * 64 + lane;
    int rl = threadIdx.x >> 6;
    int r0 = blockIdx.y * 256;
    float cm = funrep(cm_rep[col]);
    float cs = colsum[col];
    float cmax = -1.0f;
    for (int it = 0; it < 64; ++it) {
        int r = r0 + it * 4 + rl;
        float rm = funrep(rm_rep[r]);
        float rs = rowsum[r];
        size_t idx = (size_t)r * NPT + col;
        float c = C[idx];
        float p = (expf(c - cm) / cs) * (expf(c - rm) / rs);
        C[idx] = p;
        cmax = fmaxf(cmax, p);
        float wm = p;
#pragma unroll
        for (int o = 32; o; o >>= 1) wm = fmaxf(wm, __shfl_xor(wm, o));
        if (lane == 0) atomicMax(&rmp_rep[r], frep(wm));
    }
    __shared__ float red[256];
    red[threadIdx.x] = cmax;
    __syncthreads();
    if (threadIdx.x < 64) {
        float m = fmaxf(fmaxf(red[threadIdx.x], red[threadIdx.x + 64]),
                        fmaxf(red[threadIdx.x + 128], red[threadIdx.x + 192]));
        atomicMax(&cmp_rep[col], frep(m));
    }
}

// ---------- mask + first-occurrence argmax + valid + matches: block per row ----------
__global__ __launch_bounds__(256) void mask_kernel(const float* __restrict__ P,
                                                   const unsigned* __restrict__ rmp_rep,
                                                   const unsigned* __restrict__ cmp_rep,
                                                   const float* __restrict__ kpB,
                                                   float* __restrict__ maskOut,
                                                   float* __restrict__ validOut,
                                                   float* __restrict__ matchOut) {
    int n = blockIdx.x;
    float rmP = funrep(rmp_rep[n]);
    const float4* row = (const float4*)(P + (size_t)n * NPT);
    float4* mrow = (float4*)(maskOut + (size_t)n * NPT);
    int best = 0x7fffffff;
#pragma unroll
    for (int it = 0; it < 4; ++it) {
        int v4 = it * 256 + threadIdx.x;
        float4 p = row[v4];
        uint4 cmr = ((const uint4*)cmp_rep)[v4];
        int cbase = v4 * 4;
        float4 m;
        m.x = (p.x == rmP && p.x == funrep(cmr.x) && p.x > THR) ? 1.f : 0.f;
        m.y = (p.y == rmP && p.y == funrep(cmr.y) && p.y > THR) ? 1.f : 0.f;
        m.z = (p.z == rmP && p.z == funrep(cmr.z) && p.z > THR) ? 1.f : 0.f;
        m.w = (p.w == rmP && p.w == funrep(cmr.w) && p.w > THR) ? 1.f : 0.f;
        if (p.x == rmP) best = min(best, cbase + 0);
        if (p.y == rmP) best = min(best, cbase + 1);
        if (p.z == rmP) best = min(best, cbase + 2);
        if (p.w == rmP) best = min(best, cbase + 3);
        mrow[v4] = m;
    }
#pragma unroll
    for (int o = 32; o; o >>= 1) best = min(best, __shfl_xor(best, o));
    __shared__ int sb[4];
    if ((threadIdx.x & 63) == 0) sb[threadIdx.x >> 6] = best;
    __syncthreads();
    if (threadIdx.x == 0) {
        int j = min(min(sb[0], sb[1]), min(sb[2], sb[3]));
        float pj = P[(size_t)n * NPT + j];
        bool val = (pj == funrep(cmp_rep[j])) && (pj > THR);
        validOut[n] = val ? 1.f : 0.f;
        matchOut[2 * n + 0] = kpB[2 * j + 0];
        matchOut[2 * n + 1] = kpB[2 * j + 1];
    }
}

extern "C" void kernel_launch(void* const* d_in, const int* in_sizes, int n_in,
                              void* d_out, int out_size, void* d_ws, size_t ws_size,
                              hipStream_t stream) {
    const float* dA     = (const float*)d_in[1];  // descriptions_A [4096,256]
    const float* kpB    = (const float*)d_in[2];  // keypoints_B    [4096,2]
    const float* dB     = (const float*)d_in[3];  // descriptions_B [4096,256]
    const float* protos = (const float*)d_in[4];  // prototype_mats [8,256,256]

    float* P      = (float*)d_out;                  // 4096*4096
    float* maskO  = P + (size_t)NPT * NPT;          // 4096*4096
    float* validO = maskO + (size_t)NPT * NPT;      // 4096
    float* matchO = validO + NPT;                   // 4096*2

    // steered descriptors parked in the mask region (only written at the very end)
    float* steered = maskO;                         // 8*4096*256 floats = 32 MB < 64 MB

    // small stats live in ws (~260 KB needed)
    float* ws      = (float*)d_ws;
    float* a2      = ws;                 // 9*4096
    float* b2      = a2 + NVAR * NPT;    // 4096
    unsigned* rm   = (unsigned*)(b2 + NPT);
    unsigned* cm   = rm + NPT;
    float* rs      = (float*)(cm + NPT);
    float* cs      = rs + NPT;
    unsigned* rmp  = (unsigned*)(cs + NPT);
    unsigned* cmp  = rmp + NPT;

    // zero the six stat arrays (atomicMax reps start at 0 == rep(-inf-ish); sums at 0)
    hipMemsetAsync(rm, 0, 6 * NPT * sizeof(unsigned), stream);

    steer_kernel<<<dim3(64, 4, 8), 256, 0, stream>>>(dA, protos, steered);
    rownorm_kernel<<<NPT / 4, 256, 0, stream>>>(dA, a2, NPT);
    rownorm_kernel<<<(8 * NPT) / 4, 256, 0, stream>>>(steered, a2 + NPT, 8 * NPT);
    rownorm_kernel<<<NPT / 4, 256, 0, stream>>>(dB, b2, NPT);
    corr_kernel<<<dim3(64, 64), 256, 0, stream>>>(dA, steered, dB, a2, b2, P, rm, cm);
    rowsum_kernel<<<NPT, 256, 0, stream>>>(P, rm, rs);
    colsum_kernel<<<dim3(64, 16), 256, 0, stream>>>(P, cm, cs);
    p_kernel<<<dim3(64, 16), 256, 0, stream>>>(P, rm, cm, rs, cs, rmp, cmp);
    mask_kernel<<<NPT, 256, 0, stream>>>(P, rmp, cmp, kpB, maskO, validO, matchO);
}

// Round 2
// 706.063 us; speedup vs baseline: 2.0031x; 2.0031x over previous
//
#include <hip/hip_runtime.h>
#include <math.h>

#define NPT 4096
#define DIM 256
#define NVAR 9
#define INV_TEMP 20.0f
#define THR 0.01f
#define EPSD 1e-12f

typedef __attribute__((ext_vector_type(8))) __bf16 bf16x8;
typedef __attribute__((ext_vector_type(4))) float f32x4;

// ---------- helpers: order-preserving float<->uint for atomicMax on floats ----------
__device__ __forceinline__ unsigned frep(float x) {
    unsigned u = __float_as_uint(x);
    return (u & 0x80000000u) ? ~u : (u | 0x80000000u);
}
__device__ __forceinline__ float funrep(unsigned u) {
    return __uint_as_float((u & 0x80000000u) ? (u ^ 0x80000000u) : ~u);
}

// ---------- bf16 hi/lo split helpers (round-to-nearest-even) ----------
__device__ __forceinline__ unsigned short f2bf(float x) {
    unsigned u = __float_as_uint(x);
    u += 0x7fffu + ((u >> 16) & 1u);
    return (unsigned short)(u >> 16);
}
__device__ __forceinline__ float bf2f(unsigned short h) {
    return __uint_as_float(((unsigned)h) << 16);
}
__device__ __forceinline__ void split_hl(float x, unsigned short& h, unsigned short& l) {
    unsigned short hh = f2bf(x);
    h = hh;
    l = f2bf(x - bf2f(hh));  // x - bf2f(hh) is exact in fp32 (close values)
}

// ---------- async global->LDS, 16B per lane ----------
__device__ __forceinline__ void gl_lds16(const void* g, void* l) {
    __builtin_amdgcn_global_load_lds(
        (const __attribute__((address_space(1))) void*)g,
        (__attribute__((address_space(3))) void*)l, 16, 0, 0);
}

// ---------- elementwise fp32 -> (hi,lo) bf16 ----------
__global__ __launch_bounds__(256) void conv_hl_kernel(const float* __restrict__ x,
                                                      unsigned short* __restrict__ hi,
                                                      unsigned short* __restrict__ lo,
                                                      int n4) {
    int i = blockIdx.x * 256 + threadIdx.x;
    if (i >= n4) return;
    float4 v = ((const float4*)x)[i];
    ushort4 h, l;
    split_hl(v.x, h.x, l.x);
    split_hl(v.y, h.y, l.y);
    split_hl(v.z, h.z, l.z);
    split_hl(v.w, h.w, l.w);
    ((ushort4*)hi)[i] = h;
    ((ushort4*)lo)[i] = l;
}

// ---------- steering: S_k[n,e] = sum_d A[n,d]*M_k[e,d], output as hi/lo bf16 ----------
// grid (64, 4, 8), 256 threads, 64x64 tile, 4x4 microtile; variant slot k+1
__global__ __launch_bounds__(256) void steer_kernel(const float* __restrict__ A,
                                                    const float* __restrict__ protos,
                                                    unsigned short* __restrict__ Ahi,
                                                    unsigned short* __restrict__ Alo) {
    __shared__ float As[16][64];
    __shared__ float Bs[16][64];
    const int k = blockIdx.z;
    const float* B = protos + (size_t)k * DIM * DIM;
    const int tid = threadIdx.x;
    const int rb = blockIdx.x * 64, cb = blockIdx.y * 64;
    const int li = tid >> 2, lk = (tid & 3) << 2;
    const int tr = (tid >> 4) << 2, tc = (tid & 15) << 2;
    float acc[4][4] = {};
    for (int k0 = 0; k0 < DIM; k0 += 16) {
        float4 av = *(const float4*)&A[(size_t)(rb + li) * DIM + k0 + lk];
        float4 bv = *(const float4*)&B[(size_t)(cb + li) * DIM + k0 + lk];
        __syncthreads();
        As[lk + 0][li] = av.x; As[lk + 1][li] = av.y; As[lk + 2][li] = av.z; As[lk + 3][li] = av.w;
        Bs[lk + 0][li] = bv.x; Bs[lk + 1][li] = bv.y; Bs[lk + 2][li] = bv.z; Bs[lk + 3][li] = bv.w;
        __syncthreads();
#pragma unroll
        for (int kk = 0; kk < 16; ++kk) {
            float4 a = *(const float4*)&As[kk][tr];
            float4 b = *(const float4*)&Bs[kk][tc];
            const float* ap = (const float*)&a;
            const float* bp = (const float*)&b;
#pragma unroll
            for (int i = 0; i < 4; ++i)
#pragma unroll
                for (int j = 0; j < 4; ++j)
                    acc[i][j] = fmaf(ap[i], bp[j], acc[i][j]);
        }
    }
#pragma unroll
    for (int i = 0; i < 4; ++i) {
        size_t base = ((size_t)(k + 1) * NPT + rb + tr + i) * DIM + cb + tc;
        ushort4 h, l;
        split_hl(acc[i][0], h.x, l.x);
        split_hl(acc[i][1], h.y, l.y);
        split_hl(acc[i][2], h.z, l.z);
        split_hl(acc[i][3], h.w, l.w);
        *(ushort4*)&Ahi[base] = h;
        *(ushort4*)&Alo[base] = l;
    }
}

// ---------- row squared norms from hi/lo bf16: one wave per row of 256 ----------
__global__ __launch_bounds__(256) void rownorm_hl_kernel(const unsigned short* __restrict__ H,
                                                         const unsigned short* __restrict__ L,
                                                         float* __restrict__ out, int nrows) {
    int w = blockIdx.x * 4 + (threadIdx.x >> 6);
    int lane = threadIdx.x & 63;
    if (w >= nrows) return;
    ushort4 h = *(const ushort4*)&H[(size_t)w * DIM + lane * 4];
    ushort4 l = *(const ushort4*)&L[(size_t)w * DIM + lane * 4];
    float x0 = bf2f(h.x) + bf2f(l.x);
    float x1 = bf2f(h.y) + bf2f(l.y);
    float x2 = bf2f(h.z) + bf2f(l.z);
    float x3 = bf2f(h.w) + bf2f(l.w);
    float s = x0 * x0 + x1 * x1 + x2 * x2 + x3 * x3;
#pragma unroll
    for (int o = 32; o; o >>= 1) s += __shfl_xor(s, o);
    if (lane == 0) out[w] = s;
}

// ---------- main fused corr via bf16 MFMA (hi/lo x hi/lo = 4 passes) ----------
// grid (32,32), 256 threads = 4 waves; 128x128 block tile; wave tile 64x64 (4x4 frags)
__global__ __launch_bounds__(256, 2) void corr_mfma_kernel(
    const unsigned short* __restrict__ Ahi, const unsigned short* __restrict__ Alo,
    const unsigned short* __restrict__ Bhi, const unsigned short* __restrict__ Blo,
    const float* __restrict__ a2, const float* __restrict__ b2,
    float* __restrict__ cOut, unsigned* __restrict__ rm_rep, unsigned* __restrict__ cm_rep) {
    __shared__ unsigned short At[128 * 32];  // [row][k] row-major, 8 KB
    __shared__ unsigned short Bt[128 * 32];

    const int tid = threadIdx.x;
    const int lane = tid & 63;
    const int wave = tid >> 6;
    const int wr = (wave >> 1) * 64;
    const int wc = (wave & 1) * 64;
    const int rb = blockIdx.x * 128;
    const int cb = blockIdx.y * 128;
    const int l15 = lane & 15;
    const int lg = lane >> 4;       // 0..3
    const int srow = tid >> 2;      // staging row 0..63
    const int sseg = (tid & 3) * 8; // staging k-offset (ushorts)

    float b2c[4];
#pragma unroll
    for (int n = 0; n < 4; ++n) b2c[n] = b2[cb + wc + n * 16 + l15];

    f32x4 zmin[4][4];
#pragma unroll
    for (int m = 0; m < 4; ++m)
#pragma unroll
        for (int n = 0; n < 4; ++n) zmin[m][n] = 3.402823466e38f;

    for (int v = 0; v < NVAR; ++v) {
        const unsigned short* Av_h = Ahi + (size_t)v * NPT * DIM;
        const unsigned short* Av_l = Alo + (size_t)v * NPT * DIM;
        f32x4 acc[4][4];
#pragma unroll
        for (int m = 0; m < 4; ++m)
#pragma unroll
            for (int n = 0; n < 4; ++n) acc[m][n] = 0.0f;

        for (int pass = 0; pass < 4; ++pass) {
            const unsigned short* Ap = (pass & 1) ? Av_l : Av_h;
            const unsigned short* Bp = (pass & 2) ? Blo : Bhi;
            for (int k0 = 0; k0 < DIM; k0 += 32) {
                __syncthreads();  // previous tile reads complete
                gl_lds16(Ap + (size_t)(rb + srow) * DIM + k0 + sseg, &At[srow * 32 + sseg]);
                gl_lds16(Ap + (size_t)(rb + 64 + srow) * DIM + k0 + sseg, &At[(64 + srow) * 32 + sseg]);
                gl_lds16(Bp + (size_t)(cb + srow) * DIM + k0 + sseg, &Bt[srow * 32 + sseg]);
                gl_lds16(Bp + (size_t)(cb + 64 + srow) * DIM + k0 + sseg, &Bt[(64 + srow) * 32 + sseg]);
                __syncthreads();  // vmcnt(0) drained by barrier -> tile ready
                bf16x8 af[4], bfv[4];
#pragma unroll
                for (int m = 0; m < 4; ++m)
                    af[m] = *(const bf16x8*)&At[(wr + m * 16 + l15) * 32 + lg * 8];
#pragma unroll
                for (int n = 0; n < 4; ++n)
                    bfv[n] = *(const bf16x8*)&Bt[(wc + n * 16 + l15) * 32 + lg * 8];
#pragma unroll
                for (int m = 0; m < 4; ++m)
#pragma unroll
                    for (int n = 0; n < 4; ++n)
                        acc[m][n] = __builtin_amdgcn_mfma_f32_16x16x32_bf16(
                            af[m], bfv[n], acc[m][n], 0, 0, 0);
            }
        }
        // per-variant epilogue: d2 = a2 + b2 - 2*dot, clamp, min-accumulate
#pragma unroll
        for (int m = 0; m < 4; ++m) {
            float4 a4 = *(const float4*)&a2[(size_t)v * NPT + rb + wr + m * 16 + lg * 4];
            const float* a4p = (const float*)&a4;
#pragma unroll
            for (int n = 0; n < 4; ++n)
#pragma unroll
                for (int j = 0; j < 4; ++j) {
                    float d2 = fmaxf(a4p[j] + b2c[n] - 2.0f * acc[m][n][j], 0.0f);
                    zmin[m][n][j] = fminf(zmin[m][n][j], d2);
                }
        }
    }

    // epilogue: c = -20*sqrt(zmin+eps), store, row/col max via LDS then global atomics
    unsigned* redR = (unsigned*)At;
    unsigned* redC = (unsigned*)Bt;
    __syncthreads();
    if (tid < 128) { redR[tid] = 0u; redC[tid] = 0u; }
    __syncthreads();

    float colmax[4] = {-3.402823466e38f, -3.402823466e38f, -3.402823466e38f, -3.402823466e38f};
#pragma unroll
    for (int m = 0; m < 4; ++m) {
#pragma unroll
        for (int j = 0; j < 4; ++j) {
            int row = rb + wr + m * 16 + lg * 4 + j;
            float rmax = -3.402823466e38f;
#pragma unroll
            for (int n = 0; n < 4; ++n) {
                float c = -INV_TEMP * sqrtf(zmin[m][n][j] + EPSD);
                cOut[(size_t)row * NPT + cb + wc + n * 16 + l15] = c;
                rmax = fmaxf(rmax, c);
                colmax[n] = fmaxf(colmax[n], c);
            }
            atomicMax(&redR[wr + m * 16 + lg * 4 + j], frep(rmax));
        }
    }
#pragma unroll
    for (int n = 0; n < 4; ++n)
        atomicMax(&redC[wc + n * 16 + l15], frep(colmax[n]));
    __syncthreads();
    if (tid < 128) {
        atomicMax(&rm_rep[rb + tid], redR[tid]);
        atomicMax(&cm_rep[cb + tid], redC[tid]);
    }
}

// ---------- row softmax denominators: one block per row ----------
__global__ __launch_bounds__(256) void rowsum_kernel(const float* __restrict__ C,
                                                     const unsigned* __restrict__ rm_rep,
                                                     float* __restrict__ rowsum) {
    int n = blockIdx.x;
    float rm = funrep(rm_rep[n]);
    const float4* row = (const float4*)(C + (size_t)n * NPT);
    float s = 0.f;
#pragma unroll
    for (int it = 0; it < 4; ++it) {
        float4 v = row[it * 256 + threadIdx.x];
        s += expf(v.x - rm) + expf(v.y - rm) + expf(v.z - rm) + expf(v.w - rm);
    }
#pragma unroll
    for (int o = 32; o; o >>= 1) s += __shfl_xor(s, o);
    __shared__ float ws4[4];
    if ((threadIdx.x & 63) == 0) ws4[threadIdx.x >> 6] = s;
    __syncthreads();
    if (threadIdx.x == 0) rowsum[n] = (ws4[0] + ws4[1]) + (ws4[2] + ws4[3]);
}

// ---------- col softmax denominators: strip kernel, grid (64,16) ----------
__global__ __launch_bounds__(256) void colsum_kernel(const float* __restrict__ C,
                                                     const unsigned* __restrict__ cm_rep,
                                                     float* __restrict__ colsum) {
    int col = blockIdx.x * 64 + (threadIdx.x & 63);
    int rl = threadIdx.x >> 6;
    int r0 = blockIdx.y * 256;
    float cm = funrep(cm_rep[col]);
    float s = 0.f;
    for (int it = 0; it < 64; ++it) {
        int r = r0 + it * 4 + rl;
        s += expf(C[(size_t)r * NPT + col] - cm);
    }
    __shared__ float red[256];
    red[threadIdx.x] = s;
    __syncthreads();
    if (threadIdx.x < 64)
        atomicAdd(&colsum[col], (red[threadIdx.x] + red[threadIdx.x + 64]) +
                                (red[threadIdx.x + 128] + red[threadIdx.x + 192]));
}

// ---------- P = colsoftmax * rowsoftmax (in place), track row/col max of P ----------
__global__ __launch_bounds__(256) void p_kernel(float* __restrict__ C,
                                                const unsigned* __restrict__ rm_rep,
                                                const unsigned* __restrict__ cm_rep,
                                                const float* __restrict__ rowsum,
                                                const float* __restrict__ colsum,
                                                unsigned* __restrict__ rmp_rep,
                                                unsigned* __restrict__ cmp_rep) {
    int lane = threadIdx.x & 63;
    int col = blockIdx.x * 64 + lane;
    int rl = threadIdx.x >> 6;
    int r0 = blockIdx.y * 256;
    float cm = funrep(cm_rep[col]);
    float cs = colsum[col];
    float cmax = -1.0f;
    for (int it = 0; it < 64; ++it) {
        int r = r0 + it * 4 + rl;
        float rm = funrep(rm_rep[r]);
        float rs = rowsum[r];
        size_t idx = (size_t)r * NPT + col;
        float c = C[idx];
        float p = (expf(c - cm) / cs) * (expf(c - rm) / rs);
        C[idx] = p;
        cmax = fmaxf(cmax, p);
        float wm = p;
#pragma unroll
        for (int o = 32; o; o >>= 1) wm = fmaxf(wm, __shfl_xor(wm, o));
        if (lane == 0) atomicMax(&rmp_rep[r], frep(wm));
    }
    __shared__ float red[256];
    red[threadIdx.x] = cmax;
    __syncthreads();
    if (threadIdx.x < 64) {
        float m = fmaxf(fmaxf(red[threadIdx.x], red[threadIdx.x + 64]),
                        fmaxf(red[threadIdx.x + 128], red[threadIdx.x + 192]));
        atomicMax(&cmp_rep[col], frep(m));
    }
}

// ---------- mask + first-occurrence argmax + valid + matches: block per row ----------
__global__ __launch_bounds__(256) void mask_kernel(const float* __restrict__ P,
                                                   const unsigned* __restrict__ rmp_rep,
                                                   const unsigned* __restrict__ cmp_rep,
                                                   const float* __restrict__ kpB,
                                                   float* __restrict__ maskOut,
                                                   float* __restrict__ validOut,
                                                   float* __restrict__ matchOut) {
    int n = blockIdx.x;
    float rmP = funrep(rmp_rep[n]);
    const float4* row = (const float4*)(P + (size_t)n * NPT);
    float4* mrow = (float4*)(maskOut + (size_t)n * NPT);
    int best = 0x7fffffff;
#pragma unroll
    for (int it = 0; it < 4; ++it) {
        int v4 = it * 256 + threadIdx.x;
        float4 p = row[v4];
        uint4 cmr = ((const uint4*)cmp_rep)[v4];
        int cbase = v4 * 4;
        float4 m;
        m.x = (p.x == rmP && p.x == funrep(cmr.x) && p.x > THR) ? 1.f : 0.f;
        m.y = (p.y == rmP && p.y == funrep(cmr.y) && p.y > THR) ? 1.f : 0.f;
        m.z = (p.z == rmP && p.z == funrep(cmr.z) && p.z > THR) ? 1.f : 0.f;
        m.w = (p.w == rmP && p.w == funrep(cmr.w) && p.w > THR) ? 1.f : 0.f;
        if (p.x == rmP) best = min(best, cbase + 0);
        if (p.y == rmP) best = min(best, cbase + 1);
        if (p.z == rmP) best = min(best, cbase + 2);
        if (p.w == rmP) best = min(best, cbase + 3);
        mrow[v4] = m;
    }
#pragma unroll
    for (int o = 32; o; o >>= 1) best = min(best, __shfl_xor(best, o));
    __shared__ int sb[4];
    if ((threadIdx.x & 63) == 0) sb[threadIdx.x >> 6] = best;
    __syncthreads();
    if (threadIdx.x == 0) {
        int j = min(min(sb[0], sb[1]), min(sb[2], sb[3]));
        float pj = P[(size_t)n * NPT + j];
        bool val = (pj == funrep(cmp_rep[j])) && (pj > THR);
        validOut[n] = val ? 1.f : 0.f;
        matchOut[2 * n + 0] = kpB[2 * j + 0];
        matchOut[2 * n + 1] = kpB[2 * j + 1];
    }
}

extern "C" void kernel_launch(void* const* d_in, const int* in_sizes, int n_in,
                              void* d_out, int out_size, void* d_ws, size_t ws_size,
                              hipStream_t stream) {
    const float* dA     = (const float*)d_in[1];  // descriptions_A [4096,256]
    const float* kpB    = (const float*)d_in[2];  // keypoints_B    [4096,2]
    const float* dB     = (const float*)d_in[3];  // descriptions_B [4096,256]
    const float* protos = (const float*)d_in[4];  // prototype_mats [8,256,256]

    float* P      = (float*)d_out;                  // 4096*4096
    float* maskO  = P + (size_t)NPT * NPT;          // 4096*4096
    float* validO = maskO + (size_t)NPT * NPT;      // 4096
    float* matchO = validO + NPT;                   // 4096*2

    // bf16 hi/lo buffers parked in the mask region (written last): 40 MB < 64 MB
    unsigned short* Ahi = (unsigned short*)maskO;            // 9*4096*256
    unsigned short* Alo = Ahi + (size_t)NVAR * NPT * DIM;    // 9*4096*256
    unsigned short* BhiB = Alo + (size_t)NVAR * NPT * DIM;   // 4096*256
    unsigned short* BloB = BhiB + (size_t)NPT * DIM;         // 4096*256

    // small stats live in ws (~180 KB needed)
    float* ws      = (float*)d_ws;
    float* a2      = ws;                 // 9*4096
    float* b2      = a2 + NVAR * NPT;    // 4096
    unsigned* rm   = (unsigned*)(b2 + NPT);
    unsigned* cm   = rm + NPT;
    float* rs      = (float*)(cm + NPT);
    float* cs      = rs + NPT;
    unsigned* rmp  = (unsigned*)(cs + NPT);
    unsigned* cmp  = rmp + NPT;

    // zero the six stat arrays (atomicMax reps start at 0; sums at 0)
    hipMemsetAsync(rm, 0, 6 * NPT * sizeof(unsigned), stream);

    conv_hl_kernel<<<1024, 256, 0, stream>>>(dA, Ahi, Alo, NPT * DIM / 4);  // variant 0
    conv_hl_kernel<<<1024, 256, 0, stream>>>(dB, BhiB, BloB, NPT * DIM / 4);
    steer_kernel<<<dim3(64, 4, 8), 256, 0, stream>>>(dA, protos, Ahi, Alo); // variants 1..8
    rownorm_hl_kernel<<<NVAR * NPT / 4, 256, 0, stream>>>(Ahi, Alo, a2, NVAR * NPT);
    rownorm_hl_kernel<<<NPT / 4, 256, 0, stream>>>(BhiB, BloB, b2, NPT);
    corr_mfma_kernel<<<dim3(32, 32), 256, 0, stream>>>(Ahi, Alo, BhiB, BloB, a2, b2, P, rm, cm);
    rowsum_kernel<<<NPT, 256, 0, stream>>>(P, rm, rs);
    colsum_kernel<<<dim3(64, 16), 256, 0, stream>>>(P, cm, cs);
    p_kernel<<<dim3(64, 16), 256, 0, stream>>>(P, rm, cm, rs, cs, rmp, cmp);
    mask_kernel<<<NPT, 256, 0, stream>>>(P, rmp, cmp, kpB, maskO, validO, matchO);
}

// Round 3
// 589.899 us; speedup vs baseline: 2.3976x; 1.1969x over previous
//
#include <hip/hip_runtime.h>
#include <math.h>

#define NPT 4096
#define DIM 256
#define NVAR 9
#define INV_TEMP 20.0f
#define THR 0.01f
#define EPSD 1e-12f

typedef unsigned short u16;
typedef __attribute__((ext_vector_type(8))) __bf16 bf16x8;
typedef __attribute__((ext_vector_type(4))) float f32x4;

// ---------- helpers: order-preserving float<->uint for atomicMax on floats ----------
__device__ __forceinline__ unsigned frep(float x) {
    unsigned u = __float_as_uint(x);
    return (u & 0x80000000u) ? ~u : (u | 0x80000000u);
}
__device__ __forceinline__ float funrep(unsigned u) {
    return __uint_as_float((u & 0x80000000u) ? (u ^ 0x80000000u) : ~u);
}

// ---------- bf16 hi/lo split helpers (round-to-nearest-even) ----------
__device__ __forceinline__ u16 f2bf(float x) {
    unsigned u = __float_as_uint(x);
    u += 0x7fffu + ((u >> 16) & 1u);
    return (u16)(u >> 16);
}
__device__ __forceinline__ float bf2f(u16 h) {
    return __uint_as_float(((unsigned)h) << 16);
}
__device__ __forceinline__ void split_hl(float x, u16& h, u16& l) {
    u16 hh = f2bf(x);
    h = hh;
    l = f2bf(x - bf2f(hh));
}

// ---------- async global->LDS, 16B per lane ----------
__device__ __forceinline__ void gl_lds16(const void* g, void* l) {
    __builtin_amdgcn_global_load_lds(
        (const __attribute__((address_space(1))) void*)g,
        (__attribute__((address_space(3))) void*)l, 16, 0, 0);
}

// ---------- fused fp32 -> (hi,lo) bf16 for A, B, protos in one launch ----------
#define NA4 (NPT * DIM / 4)          // 262144 float4s for A and for B
#define NP4 (8 * DIM * DIM / 4)      // 131072 float4s for protos
__global__ __launch_bounds__(256) void conv3_kernel(const float* __restrict__ A,
                                                    const float* __restrict__ B,
                                                    const float* __restrict__ Pr,
                                                    u16* __restrict__ Ahi, u16* __restrict__ Alo,
                                                    u16* __restrict__ Bhi, u16* __restrict__ Blo,
                                                    u16* __restrict__ Phi, u16* __restrict__ Plo) {
    int i = blockIdx.x * 256 + threadIdx.x;
    const float* src;
    u16 *dh, *dl;
    int j;
    if (i < NA4) { src = A; dh = Ahi; dl = Alo; j = i; }
    else if (i < 2 * NA4) { src = B; dh = Bhi; dl = Blo; j = i - NA4; }
    else if (i < 2 * NA4 + NP4) { src = Pr; dh = Phi; dl = Plo; j = i - 2 * NA4; }
    else return;
    float4 v = ((const float4*)src)[j];
    ushort4 h, l;
    split_hl(v.x, h.x, l.x);
    split_hl(v.y, h.y, l.y);
    split_hl(v.z, h.z, l.z);
    split_hl(v.w, h.w, l.w);
    ((ushort4*)dh)[j] = h;
    ((ushort4*)dl)[j] = l;
}

// ---------- steering via bf16 MFMA hi/lo (3 passes): S_k = A0 * M_k^T ----------
// grid (32, 2, 8): 128x128 tile over (M=4096 rows, E=256 cols), proto k -> slot k+1
__global__ __launch_bounds__(256, 2) void steer_mfma_kernel(
    const u16* __restrict__ A0h, const u16* __restrict__ A0l,
    const u16* __restrict__ Ph, const u16* __restrict__ Pl,
    u16* __restrict__ outH, u16* __restrict__ outL) {
    __shared__ u16 lds[32768];  // 64 KB: Ah, Al, Bh, Bl each 128x64
    u16* LAh = lds;
    u16* LAl = lds + 8192;
    u16* LBh = lds + 16384;
    u16* LBl = lds + 24576;

    const int tid = threadIdx.x, lane = tid & 63, wave = tid >> 6;
    const int l15 = lane & 15, lg = lane >> 4;
    const int wr = (wave >> 1) * 64, wc = (wave & 1) * 64;
    const int rb = blockIdx.x * 128;
    const int eb = blockIdx.y * 128;
    const int k = blockIdx.z;
    const u16* Bh_g = Ph + (size_t)k * DIM * DIM;
    const u16* Bl_g = Pl + (size_t)k * DIM * DIM;
    const int s_row = tid >> 3;                 // 0..31
    const int s_ch = tid & 7;                   // LDS chunk
    const int s_gch = s_ch ^ (s_row & 7);       // swizzled global chunk
    const int c0 = lg ^ (l15 & 7);              // per-lane read chunk xor

    f32x4 acc[4][4];
#pragma unroll
    for (int m = 0; m < 4; ++m)
#pragma unroll
        for (int n = 0; n < 4; ++n) acc[m][n] = 0.0f;

    for (int kb = 0; kb < 4; ++kb) {
        const int k0 = kb * 64;
        __syncthreads();
#pragma unroll
        for (int r = 0; r < 4; ++r) {
            int row = r * 32 + s_row;
            size_t ga = (size_t)(rb + row) * DIM + k0 + s_gch * 8;
            size_t gb = (size_t)(eb + row) * DIM + k0 + s_gch * 8;
            int lo = row * 64 + s_ch * 8;
            gl_lds16(A0h + ga, &LAh[lo]);
            gl_lds16(A0l + ga, &LAl[lo]);
            gl_lds16(Bh_g + gb, &LBh[lo]);
            gl_lds16(Bl_g + gb, &LBl[lo]);
        }
        __syncthreads();
#pragma unroll
        for (int ks = 0; ks < 2; ++ks) {
            const int cx = (c0 ^ (ks << 2)) * 8;
            bf16x8 ah[4], al[4], bh[4], bl[4];
#pragma unroll
            for (int m = 0; m < 4; ++m) {
                int ro = (wr + m * 16 + l15) * 64 + cx;
                ah[m] = *(const bf16x8*)&LAh[ro];
                al[m] = *(const bf16x8*)&LAl[ro];
            }
#pragma unroll
            for (int n = 0; n < 4; ++n) {
                int ro = (wc + n * 16 + l15) * 64 + cx;
                bh[n] = *(const bf16x8*)&LBh[ro];
                bl[n] = *(const bf16x8*)&LBl[ro];
            }
#pragma unroll
            for (int m = 0; m < 4; ++m)
#pragma unroll
                for (int n = 0; n < 4; ++n)
                    acc[m][n] = __builtin_amdgcn_mfma_f32_16x16x32_bf16(ah[m], bh[n], acc[m][n], 0, 0, 0);
#pragma unroll
            for (int m = 0; m < 4; ++m)
#pragma unroll
                for (int n = 0; n < 4; ++n)
                    acc[m][n] = __builtin_amdgcn_mfma_f32_16x16x32_bf16(al[m], bh[n], acc[m][n], 0, 0, 0);
#pragma unroll
            for (int m = 0; m < 4; ++m)
#pragma unroll
                for (int n = 0; n < 4; ++n)
                    acc[m][n] = __builtin_amdgcn_mfma_f32_16x16x32_bf16(ah[m], bl[n], acc[m][n], 0, 0, 0);
        }
    }
    // epilogue: split to hi/lo, store into variant slot k+1
#pragma unroll
    for (int m = 0; m < 4; ++m)
#pragma unroll
        for (int j = 0; j < 4; ++j) {
            size_t row = (size_t)(k + 1) * NPT + rb + wr + m * 16 + lg * 4 + j;
#pragma unroll
            for (int n = 0; n < 4; ++n) {
                u16 h, l;
                split_hl(acc[m][n][j], h, l);
                size_t idx = row * DIM + eb + wc + n * 16 + l15;
                outH[idx] = h;
                outL[idx] = l;
            }
        }
}

// ---------- row squared norms for all 10*4096 rows (A variants + B) ----------
__global__ __launch_bounds__(256) void rownorm10_kernel(const u16* __restrict__ AH,
                                                        const u16* __restrict__ AL,
                                                        const u16* __restrict__ BH,
                                                        const u16* __restrict__ BL,
                                                        float* __restrict__ out) {
    int w = blockIdx.x * 4 + (threadIdx.x >> 6);
    int lane = threadIdx.x & 63;
    const u16 *H, *L;
    size_t row;
    if (w < NVAR * NPT) { H = AH; L = AL; row = w; }
    else { H = BH; L = BL; row = w - NVAR * NPT; }
    ushort4 h = *(const ushort4*)&H[row * DIM + lane * 4];
    ushort4 l = *(const ushort4*)&L[row * DIM + lane * 4];
    float x0 = bf2f(h.x) + bf2f(l.x);
    float x1 = bf2f(h.y) + bf2f(l.y);
    float x2 = bf2f(h.z) + bf2f(l.z);
    float x3 = bf2f(h.w) + bf2f(l.w);
    float s = x0 * x0 + x1 * x1 + x2 * x2 + x3 * x3;
#pragma unroll
    for (int o = 32; o; o >>= 1) s += __shfl_xor(s, o);
    if (lane == 0) out[w] = s;
}

// ---------- main fused corr via bf16 MFMA hi/lo (3 terms), 9 variants ----------
// grid (32,32) XCD-swizzled; 128x128 tile; 4 waves; K=64 chunks, 4 matrices staged
__global__ __launch_bounds__(256, 2) void corr_mfma_kernel(
    const u16* __restrict__ Ahi, const u16* __restrict__ Alo,
    const u16* __restrict__ Bhi, const u16* __restrict__ Blo,
    const float* __restrict__ a2, const float* __restrict__ b2,
    float* __restrict__ cOut, unsigned* __restrict__ rm_rep, unsigned* __restrict__ cm_rep) {
    __shared__ u16 lds[32768];  // 64 KB
    u16* LAh = lds;
    u16* LAl = lds + 8192;
    u16* LBh = lds + 16384;
    u16* LBl = lds + 24576;

    const int tid = threadIdx.x, lane = tid & 63, wave = tid >> 6;
    const int l15 = lane & 15, lg = lane >> 4;
    const int wr = (wave >> 1) * 64, wc = (wave & 1) * 64;
    // XCD-aware swizzle: 1024 wgs, 8 XCDs, 128 per XCD
    int wg = blockIdx.y * 32 + blockIdx.x;
    wg = (wg & 7) * 128 + (wg >> 3);
    const int rb = (wg >> 5) * 128;
    const int cb = (wg & 31) * 128;
    const int s_row = tid >> 3;
    const int s_ch = tid & 7;
    const int s_gch = s_ch ^ (s_row & 7);
    const int c0 = lg ^ (l15 & 7);

    float b2c[4];
#pragma unroll
    for (int n = 0; n < 4; ++n) b2c[n] = b2[cb + wc + n * 16 + l15];

    f32x4 zmin[4][4];
#pragma unroll
    for (int m = 0; m < 4; ++m)
#pragma unroll
        for (int n = 0; n < 4; ++n) zmin[m][n] = 3.402823466e38f;

    for (int v = 0; v < NVAR; ++v) {
        const u16* Ah_g = Ahi + (size_t)v * NPT * DIM;
        const u16* Al_g = Alo + (size_t)v * NPT * DIM;
        f32x4 acc[4][4];
#pragma unroll
        for (int m = 0; m < 4; ++m)
#pragma unroll
            for (int n = 0; n < 4; ++n) acc[m][n] = 0.0f;

        for (int kb = 0; kb < 4; ++kb) {
            const int k0 = kb * 64;
            __syncthreads();
#pragma unroll
            for (int r = 0; r < 4; ++r) {
                int row = r * 32 + s_row;
                size_t ga = (size_t)(rb + row) * DIM + k0 + s_gch * 8;
                size_t gb = (size_t)(cb + row) * DIM + k0 + s_gch * 8;
                int lo = row * 64 + s_ch * 8;
                gl_lds16(Ah_g + ga, &LAh[lo]);
                gl_lds16(Al_g + ga, &LAl[lo]);
                gl_lds16(Bhi + gb, &LBh[lo]);
                gl_lds16(Blo + gb, &LBl[lo]);
            }
            __syncthreads();
#pragma unroll
            for (int ks = 0; ks < 2; ++ks) {
                const int cx = (c0 ^ (ks << 2)) * 8;
                bf16x8 ah[4], al[4], bh[4], bl[4];
#pragma unroll
                for (int m = 0; m < 4; ++m) {
                    int ro = (wr + m * 16 + l15) * 64 + cx;
                    ah[m] = *(const bf16x8*)&LAh[ro];
                    al[m] = *(const bf16x8*)&LAl[ro];
                }
#pragma unroll
                for (int n = 0; n < 4; ++n) {
                    int ro = (wc + n * 16 + l15) * 64 + cx;
                    bh[n] = *(const bf16x8*)&LBh[ro];
                    bl[n] = *(const bf16x8*)&LBl[ro];
                }
#pragma unroll
                for (int m = 0; m < 4; ++m)
#pragma unroll
                    for (int n = 0; n < 4; ++n)
                        acc[m][n] = __builtin_amdgcn_mfma_f32_16x16x32_bf16(ah[m], bh[n], acc[m][n], 0, 0, 0);
#pragma unroll
                for (int m = 0; m < 4; ++m)
#pragma unroll
                    for (int n = 0; n < 4; ++n)
                        acc[m][n] = __builtin_amdgcn_mfma_f32_16x16x32_bf16(al[m], bh[n], acc[m][n], 0, 0, 0);
#pragma unroll
                for (int m = 0; m < 4; ++m)
#pragma unroll
                    for (int n = 0; n < 4; ++n)
                        acc[m][n] = __builtin_amdgcn_mfma_f32_16x16x32_bf16(ah[m], bl[n], acc[m][n], 0, 0, 0);
            }
        }
        // fold: d2 = a2 + b2 - 2*dot, clamp, min over variants
#pragma unroll
        for (int m = 0; m < 4; ++m) {
            float4 a4 = *(const float4*)&a2[(size_t)v * NPT + rb + wr + m * 16 + lg * 4];
            const float* a4p = (const float*)&a4;
#pragma unroll
            for (int n = 0; n < 4; ++n)
#pragma unroll
                for (int j = 0; j < 4; ++j) {
                    float d2 = fmaxf(a4p[j] + b2c[n] - 2.0f * acc[m][n][j], 0.0f);
                    zmin[m][n][j] = fminf(zmin[m][n][j], d2);
                }
        }
    }

    // epilogue: c = -20*sqrt(zmin+eps), store, row/col max via LDS then global atomics
    unsigned* redR = (unsigned*)lds;
    unsigned* redC = (unsigned*)(lds + 8192);
    __syncthreads();
    if (tid < 128) { redR[tid] = 0u; redC[tid] = 0u; }
    __syncthreads();

    float colmax[4] = {-3.402823466e38f, -3.402823466e38f, -3.402823466e38f, -3.402823466e38f};
#pragma unroll
    for (int m = 0; m < 4; ++m) {
#pragma unroll
        for (int j = 0; j < 4; ++j) {
            int row = rb + wr + m * 16 + lg * 4 + j;
            float rmax = -3.402823466e38f;
#pragma unroll
            for (int n = 0; n < 4; ++n) {
                float c = -INV_TEMP * sqrtf(zmin[m][n][j] + EPSD);
                cOut[(size_t)row * NPT + cb + wc + n * 16 + l15] = c;
                rmax = fmaxf(rmax, c);
                colmax[n] = fmaxf(colmax[n], c);
            }
            atomicMax(&redR[wr + m * 16 + lg * 4 + j], frep(rmax));
        }
    }
#pragma unroll
    for (int n = 0; n < 4; ++n)
        atomicMax(&redC[wc + n * 16 + l15], frep(colmax[n]));
    __syncthreads();
    if (tid < 128) {
        atomicMax(&rm_rep[rb + tid], redR[tid]);
        atomicMax(&cm_rep[cb + tid], redC[tid]);
    }
}

// ---------- fused row+col softmax denominators: one pass over C ----------
__global__ __launch_bounds__(256) void sumboth_kernel(const float* __restrict__ C,
                                                      const unsigned* __restrict__ rm_rep,
                                                      const unsigned* __restrict__ cm_rep,
                                                      float* __restrict__ rowsum,
                                                      float* __restrict__ colsum) {
    int lane = threadIdx.x & 63;
    int col = blockIdx.x * 64 + lane;
    int rl = threadIdx.x >> 6;
    int r0 = blockIdx.y * 256;
    float cm = funrep(cm_rep[col]);
    float csacc = 0.f;
    for (int it = 0; it < 64; ++it) {
        int r = r0 + it * 4 + rl;
        float c = C[(size_t)r * NPT + col];
        csacc += expf(c - cm);
        float rv = expf(c - funrep(rm_rep[r]));
#pragma unroll
        for (int o = 32; o; o >>= 1) rv += __shfl_xor(rv, o);
        if (lane == 0) atomicAdd(&rowsum[r], rv);
    }
    __shared__ float red[256];
    red[threadIdx.x] = csacc;
    __syncthreads();
    if (threadIdx.x < 64)
        atomicAdd(&colsum[col], (red[threadIdx.x] + red[threadIdx.x + 64]) +
                                (red[threadIdx.x + 128] + red[threadIdx.x + 192]));
}

// ---------- P = colsoftmax * rowsoftmax (in place), track row/col max of P ----------
__global__ __launch_bounds__(256) void p_kernel(float* __restrict__ C,
                                                const unsigned* __restrict__ rm_rep,
                                                const unsigned* __restrict__ cm_rep,
                                                const float* __restrict__ rowsum,
                                                const float* __restrict__ colsum,
                                                unsigned* __restrict__ rmp_rep,
                                                unsigned* __restrict__ cmp_rep) {
    int lane = threadIdx.x & 63;
    int col = blockIdx.x * 64 + lane;
    int rl = threadIdx.x >> 6;
    int r0 = blockIdx.y * 256;
    float cm = funrep(cm_rep[col]);
    float cs = colsum[col];
    float cmax = -1.0f;
    for (int it = 0; it < 64; ++it) {
        int r = r0 + it * 4 + rl;
        float rm = funrep(rm_rep[r]);
        float rs = rowsum[r];
        size_t idx = (size_t)r * NPT + col;
        float c = C[idx];
        float p = (expf(c - cm) / cs) * (expf(c - rm) / rs);
        C[idx] = p;
        cmax = fmaxf(cmax, p);
        float wm = p;
#pragma unroll
        for (int o = 32; o; o >>= 1) wm = fmaxf(wm, __shfl_xor(wm, o));
        if (lane == 0) atomicMax(&rmp_rep[r], frep(wm));
    }
    __shared__ float red[256];
    red[threadIdx.x] = cmax;
    __syncthreads();
    if (threadIdx.x < 64) {
        float m = fmaxf(fmaxf(red[threadIdx.x], red[threadIdx.x + 64]),
                        fmaxf(red[threadIdx.x + 128], red[threadIdx.x + 192]));
        atomicMax(&cmp_rep[col], frep(m));
    }
}

// ---------- mask + first-occurrence argmax + valid + matches: block per row ----------
__global__ __launch_bounds__(256) void mask_kernel(const float* __restrict__ P,
                                                   const unsigned* __restrict__ rmp_rep,
                                                   const unsigned* __restrict__ cmp_rep,
                                                   const float* __restrict__ kpB,
                                                   float* __restrict__ maskOut,
                                                   float* __restrict__ validOut,
                                                   float* __restrict__ matchOut) {
    int n = blockIdx.x;
    float rmP = funrep(rmp_rep[n]);
    const float4* row = (const float4*)(P + (size_t)n * NPT);
    float4* mrow = (float4*)(maskOut + (size_t)n * NPT);
    int best = 0x7fffffff;
#pragma unroll
    for (int it = 0; it < 4; ++it) {
        int v4 = it * 256 + threadIdx.x;
        float4 p = row[v4];
        uint4 cmr = ((const uint4*)cmp_rep)[v4];
        int cbase = v4 * 4;
        float4 m;
        m.x = (p.x == rmP && p.x == funrep(cmr.x) && p.x > THR) ? 1.f : 0.f;
        m.y = (p.y == rmP && p.y == funrep(cmr.y) && p.y > THR) ? 1.f : 0.f;
        m.z = (p.z == rmP && p.z == funrep(cmr.z) && p.z > THR) ? 1.f : 0.f;
        m.w = (p.w == rmP && p.w == funrep(cmr.w) && p.w > THR) ? 1.f : 0.f;
        if (p.x == rmP) best = min(best, cbase + 0);
        if (p.y == rmP) best = min(best, cbase + 1);
        if (p.z == rmP) best = min(best, cbase + 2);
        if (p.w == rmP) best = min(best, cbase + 3);
        mrow[v4] = m;
    }
#pragma unroll
    for (int o = 32; o; o >>= 1) best = min(best, __shfl_xor(best, o));
    __shared__ int sb[4];
    if ((threadIdx.x & 63) == 0) sb[threadIdx.x >> 6] = best;
    __syncthreads();
    if (threadIdx.x == 0) {
        int j = min(min(sb[0], sb[1]), min(sb[2], sb[3]));
        float pj = P[(size_t)n * NPT + j];
        bool val = (pj == funrep(cmp_rep[j])) && (pj > THR);
        validOut[n] = val ? 1.f : 0.f;
        matchOut[2 * n + 0] = kpB[2 * j + 0];
        matchOut[2 * n + 1] = kpB[2 * j + 1];
    }
}

extern "C" void kernel_launch(void* const* d_in, const int* in_sizes, int n_in,
                              void* d_out, int out_size, void* d_ws, size_t ws_size,
                              hipStream_t stream) {
    const float* dA     = (const float*)d_in[1];  // descriptions_A [4096,256]
    const float* kpB    = (const float*)d_in[2];  // keypoints_B    [4096,2]
    const float* dB     = (const float*)d_in[3];  // descriptions_B [4096,256]
    const float* protos = (const float*)d_in[4];  // prototype_mats [8,256,256]

    float* P      = (float*)d_out;                  // 4096*4096
    float* maskO  = P + (size_t)NPT * NPT;          // 4096*4096
    float* validO = maskO + (size_t)NPT * NPT;      // 4096
    float* matchO = validO + NPT;                   // 4096*2

    // bf16 hi/lo buffers parked in the mask region (written last): ~44 MB < 64 MB
    u16* Ahi = (u16*)maskO;                         // 9*4096*256
    u16* Alo = Ahi + (size_t)NVAR * NPT * DIM;
    u16* Bhi = Alo + (size_t)NVAR * NPT * DIM;      // 4096*256
    u16* Blo = Bhi + (size_t)NPT * DIM;
    u16* Phi = Blo + (size_t)NPT * DIM;             // 8*256*256
    u16* Plo = Phi + (size_t)8 * DIM * DIM;

    // small stats live in ws (256 KB)
    float* ws      = (float*)d_ws;
    float* a2      = ws;                 // 9*4096 (b2 contiguous after)
    float* b2      = a2 + NVAR * NPT;    // 4096
    unsigned* rm   = (unsigned*)(b2 + NPT);
    unsigned* cm   = rm + NPT;
    float* rs      = (float*)(cm + NPT);
    float* cs      = rs + NPT;
    unsigned* rmp  = (unsigned*)(cs + NPT);
    unsigned* cmp  = rmp + NPT;

    // zero the six stat arrays (atomic max reps at 0; sums at 0)
    hipMemsetAsync(rm, 0, 6 * NPT * sizeof(unsigned), stream);

    conv3_kernel<<<2560, 256, 0, stream>>>(dA, dB, protos, Ahi, Alo, Bhi, Blo, Phi, Plo);
    steer_mfma_kernel<<<dim3(32, 2, 8), 256, 0, stream>>>(Ahi, Alo, Phi, Plo, Ahi, Alo);
    rownorm10_kernel<<<(NVAR + 1) * NPT / 4, 256, 0, stream>>>(Ahi, Alo, Bhi, Blo, a2);
    corr_mfma_kernel<<<dim3(32, 32), 256, 0, stream>>>(Ahi, Alo, Bhi, Blo, a2, b2, P, rm, cm);
    sumboth_kernel<<<dim3(64, 16), 256, 0, stream>>>(P, rm, cm, rs, cs);
    p_kernel<<<dim3(64, 16), 256, 0, stream>>>(P, rm, cm, rs, cs, rmp, cmp);
    mask_kernel<<<NPT, 256, 0, stream>>>(P, rmp, cmp, kpB, maskO, validO, matchO);
}

// Round 5
// 429.707 us; speedup vs baseline: 3.2914x; 1.3728x over previous
//
#include <hip/hip_runtime.h>
#include <math.h>

#define NPT 4096
#define DIM 256
#define NVAR 9
#define INV_TEMP 20.0f
#define THR 0.01f
#define EPSD 1e-12f

typedef unsigned short u16;
typedef __attribute__((ext_vector_type(8))) __bf16 bf16x8;
typedef __attribute__((ext_vector_type(4))) float f32x4;

// ---------- helpers: order-preserving float<->uint for atomicMax on floats ----------
__device__ __forceinline__ unsigned frep(float x) {
    unsigned u = __float_as_uint(x);
    return (u & 0x80000000u) ? ~u : (u | 0x80000000u);
}
__device__ __forceinline__ float funrep(unsigned u) {
    return __uint_as_float((u & 0x80000000u) ? (u ^ 0x80000000u) : ~u);
}

// ---------- bf16 hi/lo split helpers (round-to-nearest-even) ----------
__device__ __forceinline__ u16 f2bf(float x) {
    unsigned u = __float_as_uint(x);
    u += 0x7fffu + ((u >> 16) & 1u);
    return (u16)(u >> 16);
}
__device__ __forceinline__ float bf2f(u16 h) {
    return __uint_as_float(((unsigned)h) << 16);
}
__device__ __forceinline__ void split_hl(float x, u16& h, u16& l) {
    u16 hh = f2bf(x);
    h = hh;
    l = f2bf(x - bf2f(hh));
}

// ---------- async global->LDS, 16B per lane ----------
__device__ __forceinline__ void gl_lds16(const void* g, void* l) {
    __builtin_amdgcn_global_load_lds(
        (const __attribute__((address_space(1))) void*)g,
        (__attribute__((address_space(3))) void*)l, 16, 0, 0);
}

// ---------- fused fp32 -> (hi,lo) bf16 for A, B, protos in one launch ----------
#define NA4 (NPT * DIM / 4)          // 262144 float4s for A and for B
#define NP4 (8 * DIM * DIM / 4)      // 131072 float4s for protos
__global__ __launch_bounds__(256) void conv3_kernel(const float* __restrict__ A,
                                                    const float* __restrict__ B,
                                                    const float* __restrict__ Pr,
                                                    u16* __restrict__ Ahi, u16* __restrict__ Alo,
                                                    u16* __restrict__ Bhi, u16* __restrict__ Blo,
                                                    u16* __restrict__ Phi, u16* __restrict__ Plo) {
    int i = blockIdx.x * 256 + threadIdx.x;
    const float* src;
    u16 *dh, *dl;
    int j;
    if (i < NA4) { src = A; dh = Ahi; dl = Alo; j = i; }
    else if (i < 2 * NA4) { src = B; dh = Bhi; dl = Blo; j = i - NA4; }
    else if (i < 2 * NA4 + NP4) { src = Pr; dh = Phi; dl = Plo; j = i - 2 * NA4; }
    else return;
    float4 v = ((const float4*)src)[j];
    ushort4 h, l;
    split_hl(v.x, h.x, l.x);
    split_hl(v.y, h.y, l.y);
    split_hl(v.z, h.z, l.z);
    split_hl(v.w, h.w, l.w);
    ((ushort4*)dh)[j] = h;
    ((ushort4*)dl)[j] = l;
}

// ---------- steering via bf16 MFMA hi/lo (3 passes): S_k = A0 * M_k^T ----------
// grid (32, 2, 8): 128x128 tile over (M=4096 rows, E=256 cols), proto k -> slot k+1
__global__ __launch_bounds__(256, 2) void steer_mfma_kernel(
    const u16* __restrict__ A0h, const u16* __restrict__ A0l,
    const u16* __restrict__ Ph, const u16* __restrict__ Pl,
    u16* __restrict__ outH, u16* __restrict__ outL) {
    __shared__ u16 lds[32768];  // 64 KB: Ah, Al, Bh, Bl each 128x64
    u16* LAh = lds;
    u16* LAl = lds + 8192;
    u16* LBh = lds + 16384;
    u16* LBl = lds + 24576;

    const int tid = threadIdx.x, lane = tid & 63, wave = tid >> 6;
    const int l15 = lane & 15, lg = lane >> 4;
    const int wr = (wave >> 1) * 64, wc = (wave & 1) * 64;
    const int rb = blockIdx.x * 128;
    const int eb = blockIdx.y * 128;
    const int k = blockIdx.z;
    const u16* Bh_g = Ph + (size_t)k * DIM * DIM;
    const u16* Bl_g = Pl + (size_t)k * DIM * DIM;
    const int s_row = tid >> 3;                 // 0..31
    const int s_ch = tid & 7;                   // LDS chunk
    const int s_gch = s_ch ^ (s_row & 7);       // swizzled global chunk
    const int c0 = lg ^ (l15 & 7);              // per-lane read chunk xor

    f32x4 acc[4][4];
#pragma unroll
    for (int m = 0; m < 4; ++m)
#pragma unroll
        for (int n = 0; n < 4; ++n) acc[m][n] = 0.0f;

    for (int kb = 0; kb < 4; ++kb) {
        const int k0 = kb * 64;
        __syncthreads();
#pragma unroll
        for (int r = 0; r < 4; ++r) {
            int row = r * 32 + s_row;
            size_t ga = (size_t)(rb + row) * DIM + k0 + s_gch * 8;
            size_t gb = (size_t)(eb + row) * DIM + k0 + s_gch * 8;
            int lo = row * 64 + s_ch * 8;
            gl_lds16(A0h + ga, &LAh[lo]);
            gl_lds16(A0l + ga, &LAl[lo]);
            gl_lds16(Bh_g + gb, &LBh[lo]);
            gl_lds16(Bl_g + gb, &LBl[lo]);
        }
        __syncthreads();
#pragma unroll
        for (int ks = 0; ks < 2; ++ks) {
            const int cx = (c0 ^ (ks << 2)) * 8;
            bf16x8 ah[4], al[4], bh[4], bl[4];
#pragma unroll
            for (int m = 0; m < 4; ++m) {
                int ro = (wr + m * 16 + l15) * 64 + cx;
                ah[m] = *(const bf16x8*)&LAh[ro];
                al[m] = *(const bf16x8*)&LAl[ro];
            }
#pragma unroll
            for (int n = 0; n < 4; ++n) {
                int ro = (wc + n * 16 + l15) * 64 + cx;
                bh[n] = *(const bf16x8*)&LBh[ro];
                bl[n] = *(const bf16x8*)&LBl[ro];
            }
#pragma unroll
            for (int m = 0; m < 4; ++m)
#pragma unroll
                for (int n = 0; n < 4; ++n)
                    acc[m][n] = __builtin_amdgcn_mfma_f32_16x16x32_bf16(ah[m], bh[n], acc[m][n], 0, 0, 0);
#pragma unroll
            for (int m = 0; m < 4; ++m)
#pragma unroll
                for (int n = 0; n < 4; ++n)
                    acc[m][n] = __builtin_amdgcn_mfma_f32_16x16x32_bf16(al[m], bh[n], acc[m][n], 0, 0, 0);
#pragma unroll
            for (int m = 0; m < 4; ++m)
#pragma unroll
                for (int n = 0; n < 4; ++n)
                    acc[m][n] = __builtin_amdgcn_mfma_f32_16x16x32_bf16(ah[m], bl[n], acc[m][n], 0, 0, 0);
        }
    }
    // epilogue: split to hi/lo, store into variant slot k+1
#pragma unroll
    for (int m = 0; m < 4; ++m)
#pragma unroll
        for (int j = 0; j < 4; ++j) {
            size_t row = (size_t)(k + 1) * NPT + rb + wr + m * 16 + lg * 4 + j;
#pragma unroll
            for (int n = 0; n < 4; ++n) {
                u16 h, l;
                split_hl(acc[m][n][j], h, l);
                size_t idx = row * DIM + eb + wc + n * 16 + l15;
                outH[idx] = h;
                outL[idx] = l;
            }
        }
}

// ---------- row squared norms for all 10*4096 rows (A variants + B) ----------
__global__ __launch_bounds__(256) void rownorm10_kernel(const u16* __restrict__ AH,
                                                        const u16* __restrict__ AL,
                                                        const u16* __restrict__ BH,
                                                        const u16* __restrict__ BL,
                                                        float* __restrict__ out) {
    int w = blockIdx.x * 4 + (threadIdx.x >> 6);
    int lane = threadIdx.x & 63;
    const u16 *H, *L;
    size_t row;
    if (w < NVAR * NPT) { H = AH; L = AL; row = w; }
    else { H = BH; L = BL; row = w - NVAR * NPT; }
    ushort4 h = *(const ushort4*)&H[row * DIM + lane * 4];
    ushort4 l = *(const ushort4*)&L[row * DIM + lane * 4];
    float x0 = bf2f(h.x) + bf2f(l.x);
    float x1 = bf2f(h.y) + bf2f(l.y);
    float x2 = bf2f(h.z) + bf2f(l.z);
    float x3 = bf2f(h.w) + bf2f(l.w);
    float s = x0 * x0 + x1 * x1 + x2 * x2 + x3 * x3;
#pragma unroll
    for (int o = 32; o; o >>= 1) s += __shfl_xor(s, o);
    if (lane == 0) out[w] = s;
}

// ---------- main fused corr via bf16 MFMA hi/lo (3 terms), 9 variants ----------
// grid (32,32) XCD-swizzled; 128x128 tile; 4 waves; K=64 chunks, 4 matrices staged
__global__ __launch_bounds__(256, 2) void corr_mfma_kernel(
    const u16* __restrict__ Ahi, const u16* __restrict__ Alo,
    const u16* __restrict__ Bhi, const u16* __restrict__ Blo,
    const float* __restrict__ a2, const float* __restrict__ b2,
    float* __restrict__ cOut, unsigned* __restrict__ rm_rep, unsigned* __restrict__ cm_rep) {
    __shared__ u16 lds[32768];  // 64 KB
    u16* LAh = lds;
    u16* LAl = lds + 8192;
    u16* LBh = lds + 16384;
    u16* LBl = lds + 24576;

    const int tid = threadIdx.x, lane = tid & 63, wave = tid >> 6;
    const int l15 = lane & 15, lg = lane >> 4;
    const int wr = (wave >> 1) * 64, wc = (wave & 1) * 64;
    // XCD-aware swizzle: 1024 wgs, 8 XCDs, 128 per XCD
    int wg = blockIdx.y * 32 + blockIdx.x;
    wg = (wg & 7) * 128 + (wg >> 3);
    const int rb = (wg >> 5) * 128;
    const int cb = (wg & 31) * 128;
    const int s_row = tid >> 3;
    const int s_ch = tid & 7;
    const int s_gch = s_ch ^ (s_row & 7);
    const int c0 = lg ^ (l15 & 7);

    float b2c[4];
#pragma unroll
    for (int n = 0; n < 4; ++n) b2c[n] = b2[cb + wc + n * 16 + l15];

    f32x4 zmin[4][4];
#pragma unroll
    for (int m = 0; m < 4; ++m)
#pragma unroll
        for (int n = 0; n < 4; ++n) zmin[m][n] = 3.402823466e38f;

    for (int v = 0; v < NVAR; ++v) {
        const u16* Ah_g = Ahi + (size_t)v * NPT * DIM;
        const u16* Al_g = Alo + (size_t)v * NPT * DIM;
        f32x4 acc[4][4];
#pragma unroll
        for (int m = 0; m < 4; ++m)
#pragma unroll
            for (int n = 0; n < 4; ++n) acc[m][n] = 0.0f;

        for (int kb = 0; kb < 4; ++kb) {
            const int k0 = kb * 64;
            __syncthreads();
#pragma unroll
            for (int r = 0; r < 4; ++r) {
                int row = r * 32 + s_row;
                size_t ga = (size_t)(rb + row) * DIM + k0 + s_gch * 8;
                size_t gb = (size_t)(cb + row) * DIM + k0 + s_gch * 8;
                int lo = row * 64 + s_ch * 8;
                gl_lds16(Ah_g + ga, &LAh[lo]);
                gl_lds16(Al_g + ga, &LAl[lo]);
                gl_lds16(Bhi + gb, &LBh[lo]);
                gl_lds16(Blo + gb, &LBl[lo]);
            }
            __syncthreads();
#pragma unroll
            for (int ks = 0; ks < 2; ++ks) {
                const int cx = (c0 ^ (ks << 2)) * 8;
                bf16x8 ah[4], al[4], bh[4], bl[4];
#pragma unroll
                for (int m = 0; m < 4; ++m) {
                    int ro = (wr + m * 16 + l15) * 64 + cx;
                    ah[m] = *(const bf16x8*)&LAh[ro];
                    al[m] = *(const bf16x8*)&LAl[ro];
                }
#pragma unroll
                for (int n = 0; n < 4; ++n) {
                    int ro = (wc + n * 16 + l15) * 64 + cx;
                    bh[n] = *(const bf16x8*)&LBh[ro];
                    bl[n] = *(const bf16x8*)&LBl[ro];
                }
#pragma unroll
                for (int m = 0; m < 4; ++m)
#pragma unroll
                    for (int n = 0; n < 4; ++n)
                        acc[m][n] = __builtin_amdgcn_mfma_f32_16x16x32_bf16(ah[m], bh[n], acc[m][n], 0, 0, 0);
#pragma unroll
                for (int m = 0; m < 4; ++m)
#pragma unroll
                    for (int n = 0; n < 4; ++n)
                        acc[m][n] = __builtin_amdgcn_mfma_f32_16x16x32_bf16(al[m], bh[n], acc[m][n], 0, 0, 0);
#pragma unroll
                for (int m = 0; m < 4; ++m)
#pragma unroll
                    for (int n = 0; n < 4; ++n)
                        acc[m][n] = __builtin_amdgcn_mfma_f32_16x16x32_bf16(ah[m], bl[n], acc[m][n], 0, 0, 0);
            }
        }
        // fold: d2 = a2 + b2 - 2*dot, clamp, min over variants
#pragma unroll
        for (int m = 0; m < 4; ++m) {
            float4 a4 = *(const float4*)&a2[(size_t)v * NPT + rb + wr + m * 16 + lg * 4];
            const float* a4p = (const float*)&a4;
#pragma unroll
            for (int n = 0; n < 4; ++n)
#pragma unroll
                for (int j = 0; j < 4; ++j) {
                    float d2 = fmaxf(a4p[j] + b2c[n] - 2.0f * acc[m][n][j], 0.0f);
                    zmin[m][n][j] = fminf(zmin[m][n][j], d2);
                }
        }
    }

    // epilogue: c = -20*sqrt(zmin+eps), store, row/col max via LDS then global atomics
    unsigned* redR = (unsigned*)lds;
    unsigned* redC = (unsigned*)(lds + 8192);
    __syncthreads();
    if (tid < 128) { redR[tid] = 0u; redC[tid] = 0u; }
    __syncthreads();

    float colmax[4] = {-3.402823466e38f, -3.402823466e38f, -3.402823466e38f, -3.402823466e38f};
#pragma unroll
    for (int m = 0; m < 4; ++m) {
#pragma unroll
        for (int j = 0; j < 4; ++j) {
            int row = rb + wr + m * 16 + lg * 4 + j;
            float rmax = -3.402823466e38f;
#pragma unroll
            for (int n = 0; n < 4; ++n) {
                float c = -INV_TEMP * sqrtf(zmin[m][n][j] + EPSD);
                cOut[(size_t)row * NPT + cb + wc + n * 16 + l15] = c;
                rmax = fmaxf(rmax, c);
                colmax[n] = fmaxf(colmax[n], c);
            }
            atomicMax(&redR[wr + m * 16 + lg * 4 + j], frep(rmax));
        }
    }
#pragma unroll
    for (int n = 0; n < 4; ++n)
        atomicMax(&redC[wc + n * 16 + l15], frep(colmax[n]));
    __syncthreads();
    if (tid < 128) {
        atomicMax(&rm_rep[rb + tid], redR[tid]);
        atomicMax(&cm_rep[cb + tid], redC[tid]);
    }
}

// ======================= restructured epilogue =======================
// Layout (all 3 big kernels): grid 1024 blocks; block owns 256 cols x 64 rows.
// Thread: 4 consecutive cols (c0 + lane*4), rows r0 + it*4 + wv, it=0..15.
// float4 loads/stores; per-thread 4-fold before wave reduces.

// pass 1: rowsum/colsum of exp(c - max)
__global__ __launch_bounds__(256) void sums_kernel(const float* __restrict__ C,
                                                   const unsigned* __restrict__ rm_rep,
                                                   const unsigned* __restrict__ cm_rep,
                                                   float* __restrict__ rowsum,
                                                   float* __restrict__ colsum) {
    const int tid = threadIdx.x, lane = tid & 63, wv = tid >> 6;
    const int c0 = (blockIdx.x & 15) * 256;
    const int r0 = (blockIdx.x >> 4) * 64;
    const int colq = (c0 >> 2) + lane;
    __shared__ float rmbuf[64];
    __shared__ float cred[4][256];
    if (tid < 64) rmbuf[tid] = funrep(rm_rep[r0 + tid]);
    uint4 cmr = ((const uint4*)cm_rep)[colq];
    float cm0 = funrep(cmr.x), cm1 = funrep(cmr.y), cm2 = funrep(cmr.z), cm3 = funrep(cmr.w);
    __syncthreads();
    float4 csa = make_float4(0.f, 0.f, 0.f, 0.f);
#pragma unroll
    for (int it = 0; it < 16; ++it) {
        int r = r0 + it * 4 + wv;
        float4 cv = ((const float4*)C)[(size_t)r * (NPT / 4) + colq];
        float rm = rmbuf[it * 4 + wv];
        float er = expf(cv.x - rm) + expf(cv.y - rm) + expf(cv.z - rm) + expf(cv.w - rm);
#pragma unroll
        for (int o = 32; o; o >>= 1) er += __shfl_xor(er, o);
        if (lane == 0) atomicAdd(&rowsum[r], er);
        csa.x += expf(cv.x - cm0);
        csa.y += expf(cv.y - cm1);
        csa.z += expf(cv.z - cm2);
        csa.w += expf(cv.w - cm3);
    }
    cred[wv][lane * 4 + 0] = csa.x;
    cred[wv][lane * 4 + 1] = csa.y;
    cred[wv][lane * 4 + 2] = csa.z;
    cred[wv][lane * 4 + 3] = csa.w;
    __syncthreads();
    float s = (cred[0][tid] + cred[1][tid]) + (cred[2][tid] + cred[3][tid]);
    atomicAdd(&colsum[c0 + tid], s);
}

// pass 2: P = colsm * rowsm (in place), track row/col max of P
__global__ __launch_bounds__(256) void pmax_kernel(float* __restrict__ C,
                                                   const unsigned* __restrict__ rm_rep,
                                                   const unsigned* __restrict__ cm_rep,
                                                   const float* __restrict__ rowsum,
                                                   const float* __restrict__ colsum,
                                                   unsigned* __restrict__ rmp_rep,
                                                   unsigned* __restrict__ cmp_rep) {
    const int tid = threadIdx.x, lane = tid & 63, wv = tid >> 6;
    const int c0 = (blockIdx.x & 15) * 256;
    const int r0 = (blockIdx.x >> 4) * 64;
    const int colq = (c0 >> 2) + lane;
    __shared__ float rmbuf[64], rsbuf[64];
    __shared__ float cred[4][256];
    if (tid < 64) {
        rmbuf[tid] = funrep(rm_rep[r0 + tid]);
        rsbuf[tid] = rowsum[r0 + tid];
    }
    uint4 cmr = ((const uint4*)cm_rep)[colq];
    float cm0 = funrep(cmr.x), cm1 = funrep(cmr.y), cm2 = funrep(cmr.z), cm3 = funrep(cmr.w);
    float4 csv = ((const float4*)colsum)[colq];
    __syncthreads();
    float4 cmax = make_float4(-1.f, -1.f, -1.f, -1.f);
#pragma unroll
    for (int it = 0; it < 16; ++it) {
        int r = r0 + it * 4 + wv;
        size_t idx = (size_t)r * (NPT / 4) + colq;
        float4 cv = ((const float4*)C)[idx];
        float rm = rmbuf[it * 4 + wv];
        float rs = rsbuf[it * 4 + wv];
        float4 p;
        p.x = (expf(cv.x - cm0) / csv.x) * (expf(cv.x - rm) / rs);
        p.y = (expf(cv.y - cm1) / csv.y) * (expf(cv.y - rm) / rs);
        p.z = (expf(cv.z - cm2) / csv.z) * (expf(cv.z - rm) / rs);
        p.w = (expf(cv.w - cm3) / csv.w) * (expf(cv.w - rm) / rs);
        ((float4*)C)[idx] = p;
        float pm = fmaxf(fmaxf(p.x, p.y), fmaxf(p.z, p.w));
#pragma unroll
        for (int o = 32; o; o >>= 1) pm = fmaxf(pm, __shfl_xor(pm, o));
        if (lane == 0) atomicMax(&rmp_rep[r], frep(pm));
        cmax.x = fmaxf(cmax.x, p.x);
        cmax.y = fmaxf(cmax.y, p.y);
        cmax.z = fmaxf(cmax.z, p.z);
        cmax.w = fmaxf(cmax.w, p.w);
    }
    cred[wv][lane * 4 + 0] = cmax.x;
    cred[wv][lane * 4 + 1] = cmax.y;
    cred[wv][lane * 4 + 2] = cmax.z;
    cred[wv][lane * 4 + 3] = cmax.w;
    __syncthreads();
    float m = fmaxf(fmaxf(cred[0][tid], cred[1][tid]), fmaxf(cred[2][tid], cred[3][tid]));
    atomicMax(&cmp_rep[c0 + tid], frep(m));
}

// pass 3: mask write + first-occurrence argmax (atomicMin on col index)
__global__ __launch_bounds__(256) void maskarg_kernel(const float* __restrict__ P,
                                                      const unsigned* __restrict__ rmp_rep,
                                                      const unsigned* __restrict__ cmp_rep,
                                                      float* __restrict__ maskOut,
                                                      int* __restrict__ argJ) {
    const int tid = threadIdx.x, lane = tid & 63, wv = tid >> 6;
    const int c0 = (blockIdx.x & 15) * 256;
    const int r0 = (blockIdx.x >> 4) * 64;
    const int colq = (c0 >> 2) + lane;
    const int col4 = c0 + lane * 4;
    __shared__ float rpbuf[64];
    if (tid < 64) rpbuf[tid] = funrep(rmp_rep[r0 + tid]);
    uint4 cpr = ((const uint4*)cmp_rep)[colq];
    float cp0 = funrep(cpr.x), cp1 = funrep(cpr.y), cp2 = funrep(cpr.z), cp3 = funrep(cpr.w);
    __syncthreads();
#pragma unroll
    for (int it = 0; it < 16; ++it) {
        int r = r0 + it * 4 + wv;
        size_t idx = (size_t)r * (NPT / 4) + colq;
        float4 p = ((const float4*)P)[idx];
        float rmp = rpbuf[it * 4 + wv];
        float4 m;
        m.x = (p.x == rmp && p.x == cp0 && p.x > THR) ? 1.f : 0.f;
        m.y = (p.y == rmp && p.y == cp1 && p.y > THR) ? 1.f : 0.f;
        m.z = (p.z == rmp && p.z == cp2 && p.z > THR) ? 1.f : 0.f;
        m.w = (p.w == rmp && p.w == cp3 && p.w > THR) ? 1.f : 0.f;
        ((float4*)maskOut)[idx] = m;
        int cand = 0x7fffffff;
        if (p.w == rmp) cand = col4 + 3;
        if (p.z == rmp) cand = col4 + 2;
        if (p.y == rmp) cand = col4 + 1;
        if (p.x == rmp) cand = col4 + 0;
#pragma unroll
        for (int o = 32; o; o >>= 1) cand = min(cand, __shfl_xor(cand, o));
        if (lane == 0) atomicMin(&argJ[r], cand);
    }
}

// pass 4: valid flag + matched keypoints (tiny)
__global__ __launch_bounds__(256) void valid_kernel(const float* __restrict__ P,
                                                    const unsigned* __restrict__ cmp_rep,
                                                    const int* __restrict__ argJ,
                                                    const float* __restrict__ kpB,
                                                    float* __restrict__ validOut,
                                                    float* __restrict__ matchOut) {
    int n = blockIdx.x * 256 + threadIdx.x;
    int j = argJ[n];
    float pj = P[(size_t)n * NPT + j];
    bool v = (pj == funrep(cmp_rep[j])) && (pj > THR);
    validOut[n] = v ? 1.f : 0.f;
    matchOut[2 * n + 0] = kpB[2 * j + 0];
    matchOut[2 * n + 1] = kpB[2 * j + 1];
}

extern "C" void kernel_launch(void* const* d_in, const int* in_sizes, int n_in,
                              void* d_out, int out_size, void* d_ws, size_t ws_size,
                              hipStream_t stream) {
    const float* dA     = (const float*)d_in[1];  // descriptions_A [4096,256]
    const float* kpB    = (const float*)d_in[2];  // keypoints_B    [4096,2]
    const float* dB     = (const float*)d_in[3];  // descriptions_B [4096,256]
    const float* protos = (const float*)d_in[4];  // prototype_mats [8,256,256]

    float* P      = (float*)d_out;                  // 4096*4096
    float* maskO  = P + (size_t)NPT * NPT;          // 4096*4096
    float* validO = maskO + (size_t)NPT * NPT;      // 4096
    float* matchO = validO + NPT;                   // 4096*2

    // bf16 hi/lo buffers parked in the mask region (written last): ~44 MB < 64 MB
    u16* Ahi = (u16*)maskO;                         // 9*4096*256
    u16* Alo = Ahi + (size_t)NVAR * NPT * DIM;
    u16* Bhi = Alo + (size_t)NVAR * NPT * DIM;      // 4096*256
    u16* Blo = Bhi + (size_t)NPT * DIM;
    u16* Phi = Blo + (size_t)NPT * DIM;             // 8*256*256
    u16* Plo = Phi + (size_t)8 * DIM * DIM;

    // small stats live in ws (~280 KB)
    float* ws      = (float*)d_ws;
    float* a2      = ws;                 // 9*4096
    float* b2      = a2 + NVAR * NPT;    // 4096
    unsigned* rm   = (unsigned*)(b2 + NPT);
    unsigned* cm   = rm + NPT;
    float* rs      = (float*)(cm + NPT);
    float* cs      = rs + NPT;
    unsigned* rmp  = (unsigned*)(cs + NPT);
    unsigned* cmp  = rmp + NPT;
    int* argJ      = (int*)(cmp + NPT);

    // zero the six stat arrays; argJ to big sentinel (0x7f7f7f7f)
    hipMemsetAsync(rm, 0, 6 * NPT * sizeof(unsigned), stream);
    hipMemsetAsync(argJ, 0x7f, NPT * sizeof(int), stream);

    conv3_kernel<<<2560, 256, 0, stream>>>(dA, dB, protos, Ahi, Alo, Bhi, Blo, Phi, Plo);
    steer_mfma_kernel<<<dim3(32, 2, 8), 256, 0, stream>>>(Ahi, Alo, Phi, Plo, Ahi, Alo);
    rownorm10_kernel<<<(NVAR + 1) * NPT / 4, 256, 0, stream>>>(Ahi, Alo, Bhi, Blo, a2);
    corr_mfma_kernel<<<dim3(32, 32), 256, 0, stream>>>(Ahi, Alo, Bhi, Blo, a2, b2, P, rm, cm);
    sums_kernel<<<1024, 256, 0, stream>>>(P, rm, cm, rs, cs);
    pmax_kernel<<<1024, 256, 0, stream>>>(P, rm, cm, rs, cs, rmp, cmp);
    maskarg_kernel<<<1024, 256, 0, stream>>>(P, rmp, cmp, maskO, argJ);
    valid_kernel<<<16, 256, 0, stream>>>(P, cmp, argJ, kpB, validO, matchO);
}

// Round 6
// 408.857 us; speedup vs baseline: 3.4592x; 1.0510x over previous
//
#include <hip/hip_runtime.h>
#include <math.h>

#define NPT 4096
#define DIM 256
#define NVAR 9
#define INV_TEMP 20.0f
#define THR 0.01f
#define EPSD 1e-12f

typedef unsigned short u16;
typedef __attribute__((ext_vector_type(8))) __bf16 bf16x8;
typedef __attribute__((ext_vector_type(4))) float f32x4;

// ---------- helpers: order-preserving float<->uint for atomicMax on floats ----------
__device__ __forceinline__ unsigned frep(float x) {
    unsigned u = __float_as_uint(x);
    return (u & 0x80000000u) ? ~u : (u | 0x80000000u);
}
__device__ __forceinline__ float funrep(unsigned u) {
    return __uint_as_float((u & 0x80000000u) ? (u ^ 0x80000000u) : ~u);
}

// ---------- bf16 hi/lo split helpers (round-to-nearest-even) ----------
__device__ __forceinline__ u16 f2bf(float x) {
    unsigned u = __float_as_uint(x);
    u += 0x7fffu + ((u >> 16) & 1u);
    return (u16)(u >> 16);
}
__device__ __forceinline__ float bf2f(u16 h) {
    return __uint_as_float(((unsigned)h) << 16);
}
__device__ __forceinline__ void split_hl(float x, u16& h, u16& l) {
    u16 hh = f2bf(x);
    h = hh;
    l = f2bf(x - bf2f(hh));
}

// ---------- async global->LDS, 16B per lane ----------
__device__ __forceinline__ void gl_lds16(const void* g, void* l) {
    __builtin_amdgcn_global_load_lds(
        (const __attribute__((address_space(1))) void*)g,
        (__attribute__((address_space(3))) void*)l, 16, 0, 0);
}

// ---------- fused fp32 -> (hi,lo) bf16 for A, B, protos in one launch ----------
#define NA4 (NPT * DIM / 4)          // 262144 float4s for A and for B
#define NP4 (8 * DIM * DIM / 4)      // 131072 float4s for protos
__global__ __launch_bounds__(256) void conv3_kernel(const float* __restrict__ A,
                                                    const float* __restrict__ B,
                                                    const float* __restrict__ Pr,
                                                    u16* __restrict__ Ahi, u16* __restrict__ Alo,
                                                    u16* __restrict__ Bhi, u16* __restrict__ Blo,
                                                    u16* __restrict__ Phi, u16* __restrict__ Plo) {
    int i = blockIdx.x * 256 + threadIdx.x;
    const float* src;
    u16 *dh, *dl;
    int j;
    if (i < NA4) { src = A; dh = Ahi; dl = Alo; j = i; }
    else if (i < 2 * NA4) { src = B; dh = Bhi; dl = Blo; j = i - NA4; }
    else if (i < 2 * NA4 + NP4) { src = Pr; dh = Phi; dl = Plo; j = i - 2 * NA4; }
    else return;
    float4 v = ((const float4*)src)[j];
    ushort4 h, l;
    split_hl(v.x, h.x, l.x);
    split_hl(v.y, h.y, l.y);
    split_hl(v.z, h.z, l.z);
    split_hl(v.w, h.w, l.w);
    ((ushort4*)dh)[j] = h;
    ((ushort4*)dl)[j] = l;
}

// ---------- steering via bf16 MFMA hi/lo (3 passes): S_k = A0 * M_k^T ----------
// grid (32, 2, 8): 128x128 tile over (M=4096 rows, E=256 cols), proto k -> slot k+1
__global__ __launch_bounds__(256, 2) void steer_mfma_kernel(
    const u16* __restrict__ A0h, const u16* __restrict__ A0l,
    const u16* __restrict__ Ph, const u16* __restrict__ Pl,
    u16* __restrict__ outH, u16* __restrict__ outL) {
    __shared__ u16 lds[32768];  // 64 KB: Ah, Al, Bh, Bl each 128x64
    u16* LAh = lds;
    u16* LAl = lds + 8192;
    u16* LBh = lds + 16384;
    u16* LBl = lds + 24576;

    const int tid = threadIdx.x, lane = tid & 63, wave = tid >> 6;
    const int l15 = lane & 15, lg = lane >> 4;
    const int wr = (wave >> 1) * 64, wc = (wave & 1) * 64;
    const int rb = blockIdx.x * 128;
    const int eb = blockIdx.y * 128;
    const int k = blockIdx.z;
    const u16* Bh_g = Ph + (size_t)k * DIM * DIM;
    const u16* Bl_g = Pl + (size_t)k * DIM * DIM;
    const int s_row = tid >> 3;                 // 0..31
    const int s_ch = tid & 7;                   // LDS chunk
    const int s_gch = s_ch ^ (s_row & 7);       // swizzled global chunk
    const int c0 = lg ^ (l15 & 7);              // per-lane read chunk xor

    f32x4 acc[4][4];
#pragma unroll
    for (int m = 0; m < 4; ++m)
#pragma unroll
        for (int n = 0; n < 4; ++n) acc[m][n] = 0.0f;

    for (int kb = 0; kb < 4; ++kb) {
        const int k0 = kb * 64;
        __syncthreads();
#pragma unroll
        for (int r = 0; r < 4; ++r) {
            int row = r * 32 + s_row;
            size_t ga = (size_t)(rb + row) * DIM + k0 + s_gch * 8;
            size_t gb = (size_t)(eb + row) * DIM + k0 + s_gch * 8;
            int lo = row * 64 + s_ch * 8;
            gl_lds16(A0h + ga, &LAh[lo]);
            gl_lds16(A0l + ga, &LAl[lo]);
            gl_lds16(Bh_g + gb, &LBh[lo]);
            gl_lds16(Bl_g + gb, &LBl[lo]);
        }
        __syncthreads();
#pragma unroll
        for (int ks = 0; ks < 2; ++ks) {
            const int cx = (c0 ^ (ks << 2)) * 8;
            bf16x8 ah[4], al[4], bh[4], bl[4];
#pragma unroll
            for (int m = 0; m < 4; ++m) {
                int ro = (wr + m * 16 + l15) * 64 + cx;
                ah[m] = *(const bf16x8*)&LAh[ro];
                al[m] = *(const bf16x8*)&LAl[ro];
            }
#pragma unroll
            for (int n = 0; n < 4; ++n) {
                int ro = (wc + n * 16 + l15) * 64 + cx;
                bh[n] = *(const bf16x8*)&LBh[ro];
                bl[n] = *(const bf16x8*)&LBl[ro];
            }
#pragma unroll
            for (int m = 0; m < 4; ++m)
#pragma unroll
                for (int n = 0; n < 4; ++n)
                    acc[m][n] = __builtin_amdgcn_mfma_f32_16x16x32_bf16(ah[m], bh[n], acc[m][n], 0, 0, 0);
#pragma unroll
            for (int m = 0; m < 4; ++m)
#pragma unroll
                for (int n = 0; n < 4; ++n)
                    acc[m][n] = __builtin_amdgcn_mfma_f32_16x16x32_bf16(al[m], bh[n], acc[m][n], 0, 0, 0);
#pragma unroll
            for (int m = 0; m < 4; ++m)
#pragma unroll
                for (int n = 0; n < 4; ++n)
                    acc[m][n] = __builtin_amdgcn_mfma_f32_16x16x32_bf16(ah[m], bl[n], acc[m][n], 0, 0, 0);
        }
    }
    // epilogue: split to hi/lo, store into variant slot k+1
#pragma unroll
    for (int m = 0; m < 4; ++m)
#pragma unroll
        for (int j = 0; j < 4; ++j) {
            size_t row = (size_t)(k + 1) * NPT + rb + wr + m * 16 + lg * 4 + j;
#pragma unroll
            for (int n = 0; n < 4; ++n) {
                u16 h, l;
                split_hl(acc[m][n][j], h, l);
                size_t idx = row * DIM + eb + wc + n * 16 + l15;
                outH[idx] = h;
                outL[idx] = l;
            }
        }
}

// ---------- row squared norms for all 10*4096 rows (A variants + B) ----------
__global__ __launch_bounds__(256) void rownorm10_kernel(const u16* __restrict__ AH,
                                                        const u16* __restrict__ AL,
                                                        const u16* __restrict__ BH,
                                                        const u16* __restrict__ BL,
                                                        float* __restrict__ out) {
    int w = blockIdx.x * 4 + (threadIdx.x >> 6);
    int lane = threadIdx.x & 63;
    const u16 *H, *L;
    size_t row;
    if (w < NVAR * NPT) { H = AH; L = AL; row = w; }
    else { H = BH; L = BL; row = w - NVAR * NPT; }
    ushort4 h = *(const ushort4*)&H[row * DIM + lane * 4];
    ushort4 l = *(const ushort4*)&L[row * DIM + lane * 4];
    float x0 = bf2f(h.x) + bf2f(l.x);
    float x1 = bf2f(h.y) + bf2f(l.y);
    float x2 = bf2f(h.z) + bf2f(l.z);
    float x3 = bf2f(h.w) + bf2f(l.w);
    float s = x0 * x0 + x1 * x1 + x2 * x2 + x3 * x3;
#pragma unroll
    for (int o = 32; o; o >>= 1) s += __shfl_xor(s, o);
    if (lane == 0) out[w] = s;
}

// ---------- main fused corr via bf16 MFMA hi/lo (3 terms), 9 variants ----------
// grid (32,32) XCD-swizzled; 128x128 tile; 4 waves; K=64 chunks, 4 matrices staged
// Epilogue additionally computes per-block softmax partials (max,sum) per row/col.
__global__ __launch_bounds__(256, 2) void corr_mfma_kernel(
    const u16* __restrict__ Ahi, const u16* __restrict__ Alo,
    const u16* __restrict__ Bhi, const u16* __restrict__ Blo,
    const float* __restrict__ a2, const float* __restrict__ b2,
    float* __restrict__ cOut, unsigned* __restrict__ rm_rep, unsigned* __restrict__ cm_rep,
    float* __restrict__ pMaxR, float* __restrict__ pSumR,
    float* __restrict__ pMaxC, float* __restrict__ pSumC) {
    __shared__ u16 lds[32768];  // 64 KB
    u16* LAh = lds;
    u16* LAl = lds + 8192;
    u16* LBh = lds + 16384;
    u16* LBl = lds + 24576;

    const int tid = threadIdx.x, lane = tid & 63, wave = tid >> 6;
    const int l15 = lane & 15, lg = lane >> 4;
    const int wr = (wave >> 1) * 64, wc = (wave & 1) * 64;
    // XCD-aware swizzle: 1024 wgs, 8 XCDs, 128 per XCD
    int wg = blockIdx.y * 32 + blockIdx.x;
    wg = (wg & 7) * 128 + (wg >> 3);
    const int rb = (wg >> 5) * 128;
    const int cb = (wg & 31) * 128;
    const int rbIdx = rb >> 7, cbIdx = cb >> 7;
    const int s_row = tid >> 3;
    const int s_ch = tid & 7;
    const int s_gch = s_ch ^ (s_row & 7);
    const int c0 = lg ^ (l15 & 7);

    float b2c[4];
#pragma unroll
    for (int n = 0; n < 4; ++n) b2c[n] = b2[cb + wc + n * 16 + l15];

    f32x4 zmin[4][4];
#pragma unroll
    for (int m = 0; m < 4; ++m)
#pragma unroll
        for (int n = 0; n < 4; ++n) zmin[m][n] = 3.402823466e38f;

    for (int v = 0; v < NVAR; ++v) {
        const u16* Ah_g = Ahi + (size_t)v * NPT * DIM;
        const u16* Al_g = Alo + (size_t)v * NPT * DIM;
        f32x4 acc[4][4];
#pragma unroll
        for (int m = 0; m < 4; ++m)
#pragma unroll
            for (int n = 0; n < 4; ++n) acc[m][n] = 0.0f;

        for (int kb = 0; kb < 4; ++kb) {
            const int k0 = kb * 64;
            __syncthreads();
#pragma unroll
            for (int r = 0; r < 4; ++r) {
                int row = r * 32 + s_row;
                size_t ga = (size_t)(rb + row) * DIM + k0 + s_gch * 8;
                size_t gb = (size_t)(cb + row) * DIM + k0 + s_gch * 8;
                int lo = row * 64 + s_ch * 8;
                gl_lds16(Ah_g + ga, &LAh[lo]);
                gl_lds16(Al_g + ga, &LAl[lo]);
                gl_lds16(Bhi + gb, &LBh[lo]);
                gl_lds16(Blo + gb, &LBl[lo]);
            }
            __syncthreads();
#pragma unroll
            for (int ks = 0; ks < 2; ++ks) {
                const int cx = (c0 ^ (ks << 2)) * 8;
                bf16x8 ah[4], al[4], bh[4], bl[4];
#pragma unroll
                for (int m = 0; m < 4; ++m) {
                    int ro = (wr + m * 16 + l15) * 64 + cx;
                    ah[m] = *(const bf16x8*)&LAh[ro];
                    al[m] = *(const bf16x8*)&LAl[ro];
                }
#pragma unroll
                for (int n = 0; n < 4; ++n) {
                    int ro = (wc + n * 16 + l15) * 64 + cx;
                    bh[n] = *(const bf16x8*)&LBh[ro];
                    bl[n] = *(const bf16x8*)&LBl[ro];
                }
#pragma unroll
                for (int m = 0; m < 4; ++m)
#pragma unroll
                    for (int n = 0; n < 4; ++n)
                        acc[m][n] = __builtin_amdgcn_mfma_f32_16x16x32_bf16(ah[m], bh[n], acc[m][n], 0, 0, 0);
#pragma unroll
                for (int m = 0; m < 4; ++m)
#pragma unroll
                    for (int n = 0; n < 4; ++n)
                        acc[m][n] = __builtin_amdgcn_mfma_f32_16x16x32_bf16(al[m], bh[n], acc[m][n], 0, 0, 0);
#pragma unroll
                for (int m = 0; m < 4; ++m)
#pragma unroll
                    for (int n = 0; n < 4; ++n)
                        acc[m][n] = __builtin_amdgcn_mfma_f32_16x16x32_bf16(ah[m], bl[n], acc[m][n], 0, 0, 0);
            }
        }
        // fold: d2 = a2 + b2 - 2*dot, clamp, min over variants
#pragma unroll
        for (int m = 0; m < 4; ++m) {
            float4 a4 = *(const float4*)&a2[(size_t)v * NPT + rb + wr + m * 16 + lg * 4];
            const float* a4p = (const float*)&a4;
#pragma unroll
            for (int n = 0; n < 4; ++n)
#pragma unroll
                for (int j = 0; j < 4; ++j) {
                    float d2 = fmaxf(a4p[j] + b2c[n] - 2.0f * acc[m][n][j], 0.0f);
                    zmin[m][n][j] = fminf(zmin[m][n][j], d2);
                }
        }
    }

    // ---- epilogue pass 1: c = -20*sqrt(zmin+eps), store C, block-local row/col max ----
    unsigned* redR = (unsigned*)lds;          // 128
    unsigned* redC = redR + 128;              // 128
    float* bsumR = (float*)(redC + 128);      // 128
    float* bsumC = bsumR + 128;               // 128
    __syncthreads();
    if (tid < 128) { redR[tid] = 0u; redC[tid] = 0u; bsumR[tid] = 0.f; bsumC[tid] = 0.f; }
    __syncthreads();

    float colmax[4] = {-3.402823466e38f, -3.402823466e38f, -3.402823466e38f, -3.402823466e38f};
#pragma unroll
    for (int m = 0; m < 4; ++m) {
#pragma unroll
        for (int j = 0; j < 4; ++j) {
            int row = rb + wr + m * 16 + lg * 4 + j;
            float rmax = -3.402823466e38f;
#pragma unroll
            for (int n = 0; n < 4; ++n) {
                float c = -INV_TEMP * sqrtf(zmin[m][n][j] + EPSD);
                cOut[(size_t)row * NPT + cb + wc + n * 16 + l15] = c;
                rmax = fmaxf(rmax, c);
                colmax[n] = fmaxf(colmax[n], c);
            }
            atomicMax(&redR[wr + m * 16 + lg * 4 + j], frep(rmax));
        }
    }
#pragma unroll
    for (int n = 0; n < 4; ++n)
        atomicMax(&redC[wc + n * 16 + l15], frep(colmax[n]));
    __syncthreads();

    // ---- epilogue pass 2: block-local exp-sums relative to block max ----
    float bmc[4], colS[4];
#pragma unroll
    for (int n = 0; n < 4; ++n) {
        bmc[n] = funrep(redC[wc + n * 16 + l15]);
        colS[n] = 0.f;
    }
#pragma unroll
    for (int m = 0; m < 4; ++m) {
#pragma unroll
        for (int j = 0; j < 4; ++j) {
            int lr = wr + m * 16 + lg * 4 + j;
            float bm = funrep(redR[lr]);
            float s = 0.f;
#pragma unroll
            for (int n = 0; n < 4; ++n) {
                float c = -INV_TEMP * sqrtf(zmin[m][n][j] + EPSD);
                s += __expf(c - bm);
                colS[n] += __expf(c - bmc[n]);
            }
            // reduce over the 16-lane l15 group (covers 64 cols of this row)
            s += __shfl_xor(s, 1);
            s += __shfl_xor(s, 2);
            s += __shfl_xor(s, 4);
            s += __shfl_xor(s, 8);
            if (l15 == 0) atomicAdd(&bsumR[lr], s);
        }
    }
#pragma unroll
    for (int n = 0; n < 4; ++n) {
        float s = colS[n];
        // reduce over lg (lanes differing in bits 4,5)
        s += __shfl_xor(s, 16);
        s += __shfl_xor(s, 32);
        if (lg == 0) atomicAdd(&bsumC[wc + n * 16 + l15], s);
    }
    __syncthreads();

    // ---- epilogue pass 3: global max atomics + per-block partial writes ----
    if (tid < 128) {
        atomicMax(&rm_rep[rb + tid], redR[tid]);
        pMaxR[(size_t)cbIdx * NPT + rb + tid] = funrep(redR[tid]);
        pSumR[(size_t)cbIdx * NPT + rb + tid] = bsumR[tid];
    } else {
        int t = tid - 128;
        atomicMax(&cm_rep[cb + t], redC[t]);
        pMaxC[(size_t)rbIdx * NPT + cb + t] = funrep(redC[t]);
        pSumC[(size_t)rbIdx * NPT + cb + t] = bsumC[t];
    }
}

// ---------- combine per-block partials into rowsum/colsum (replaces sums pass) ----------
__global__ __launch_bounds__(256) void combine_kernel(const unsigned* __restrict__ rm_rep,
                                                      const unsigned* __restrict__ cm_rep,
                                                      const float* __restrict__ pMaxR,
                                                      const float* __restrict__ pSumR,
                                                      const float* __restrict__ pMaxC,
                                                      const float* __restrict__ pSumC,
                                                      float* __restrict__ rowsum,
                                                      float* __restrict__ colsum) {
    int idx = (blockIdx.x & 15) * 256 + threadIdx.x;
    if (blockIdx.x < 16) {
        float gm = funrep(rm_rep[idx]);
        float s = 0.f;
#pragma unroll
        for (int b = 0; b < 32; ++b)
            s += pSumR[(size_t)b * NPT + idx] * __expf(pMaxR[(size_t)b * NPT + idx] - gm);
        rowsum[idx] = s;
    } else {
        float gm = funrep(cm_rep[idx]);
        float s = 0.f;
#pragma unroll
        for (int b = 0; b < 32; ++b)
            s += pSumC[(size_t)b * NPT + idx] * __expf(pMaxC[(size_t)b * NPT + idx] - gm);
        colsum[idx] = s;
    }
}

// ======================= streaming epilogue =======================
// grid 1024 blocks; block owns 256 cols x 64 rows. Thread: 4 consecutive cols
// (c0 + lane*4), rows r0 + it*4 + wv, it=0..15. float4 I/O throughout.

// pass A: P = exp(2c - cm - rm)/(cs*rs) in place, track row/col max of P
__global__ __launch_bounds__(256) void pmax_kernel(float* __restrict__ C,
                                                   const unsigned* __restrict__ rm_rep,
                                                   const unsigned* __restrict__ cm_rep,
                                                   const float* __restrict__ rowsum,
                                                   const float* __restrict__ colsum,
                                                   unsigned* __restrict__ rmp_rep,
                                                   unsigned* __restrict__ cmp_rep) {
    const int tid = threadIdx.x, lane = tid & 63, wv = tid >> 6;
    const int c0 = (blockIdx.x & 15) * 256;
    const int r0 = (blockIdx.x >> 4) * 64;
    const int colq = (c0 >> 2) + lane;
    __shared__ float rmbuf[64], rrbuf[64];
    __shared__ float pmLds[64 * 65];
    __shared__ float qred[256];
    __shared__ float cred[4][256];
    if (tid < 64) {
        rmbuf[tid] = funrep(rm_rep[r0 + tid]);
        rrbuf[tid] = 1.0f / rowsum[r0 + tid];
    }
    uint4 cmr = ((const uint4*)cm_rep)[colq];
    float cm0 = funrep(cmr.x), cm1 = funrep(cmr.y), cm2 = funrep(cmr.z), cm3 = funrep(cmr.w);
    float4 csv = ((const float4*)colsum)[colq];
    float rc0 = 1.0f / csv.x, rc1 = 1.0f / csv.y, rc2 = 1.0f / csv.z, rc3 = 1.0f / csv.w;
    __syncthreads();
    float4 cmax = make_float4(-1.f, -1.f, -1.f, -1.f);
#pragma unroll
    for (int it = 0; it < 16; ++it) {
        int lr = it * 4 + wv;
        int r = r0 + lr;
        size_t idx = (size_t)r * (NPT / 4) + colq;
        float4 cv = ((const float4*)C)[idx];
        float rm = rmbuf[lr];
        float rr = rrbuf[lr];
        float4 p;
        p.x = __expf(2.0f * cv.x - cm0 - rm) * (rc0 * rr);
        p.y = __expf(2.0f * cv.y - cm1 - rm) * (rc1 * rr);
        p.z = __expf(2.0f * cv.z - cm2 - rm) * (rc2 * rr);
        p.w = __expf(2.0f * cv.w - cm3 - rm) * (rc3 * rr);
        ((float4*)C)[idx] = p;
        pmLds[lr * 65 + lane] = fmaxf(fmaxf(p.x, p.y), fmaxf(p.z, p.w));
        cmax.x = fmaxf(cmax.x, p.x);
        cmax.y = fmaxf(cmax.y, p.y);
        cmax.z = fmaxf(cmax.z, p.z);
        cmax.w = fmaxf(cmax.w, p.w);
    }
    cred[wv][lane * 4 + 0] = cmax.x;
    cred[wv][lane * 4 + 1] = cmax.y;
    cred[wv][lane * 4 + 2] = cmax.z;
    cred[wv][lane * 4 + 3] = cmax.w;
    __syncthreads();
    {
        int row = tid & 63, q = tid >> 6;
        float m = -1.f;
#pragma unroll
        for (int i = 0; i < 16; ++i) m = fmaxf(m, pmLds[row * 65 + q * 16 + i]);
        qred[row * 4 + q] = m;
    }
    float mc = fmaxf(fmaxf(cred[0][tid], cred[1][tid]), fmaxf(cred[2][tid], cred[3][tid]));
    atomicMax(&cmp_rep[c0 + tid], frep(mc));
    __syncthreads();
    if (tid < 64) {
        float m = fmaxf(fmaxf(qred[tid * 4 + 0], qred[tid * 4 + 1]),
                        fmaxf(qred[tid * 4 + 2], qred[tid * 4 + 3]));
        atomicMax(&rmp_rep[r0 + tid], frep(m));
    }
}

// pass B: mask write + first-occurrence argmax (atomicMin on col index)
__global__ __launch_bounds__(256) void maskarg_kernel(const float* __restrict__ P,
                                                      const unsigned* __restrict__ rmp_rep,
                                                      const unsigned* __restrict__ cmp_rep,
                                                      float* __restrict__ maskOut,
                                                      int* __restrict__ argJ) {
    const int tid = threadIdx.x, lane = tid & 63, wv = tid >> 6;
    const int c0 = (blockIdx.x & 15) * 256;
    const int r0 = (blockIdx.x >> 4) * 64;
    const int colq = (c0 >> 2) + lane;
    const int col4 = c0 + lane * 4;
    __shared__ float rpbuf[64];
    __shared__ int candLds[64 * 65];
    __shared__ int qredi[256];
    if (tid < 64) rpbuf[tid] = funrep(rmp_rep[r0 + tid]);
    uint4 cpr = ((const uint4*)cmp_rep)[colq];
    float cp0 = funrep(cpr.x), cp1 = funrep(cpr.y), cp2 = funrep(cpr.z), cp3 = funrep(cpr.w);
    __syncthreads();
#pragma unroll
    for (int it = 0; it < 16; ++it) {
        int lr = it * 4 + wv;
        int r = r0 + lr;
        size_t idx = (size_t)r * (NPT / 4) + colq;
        float4 p = ((const float4*)P)[idx];
        float rmp = rpbuf[lr];
        float4 m;
        m.x = (p.x == rmp && p.x == cp0 && p.x > THR) ? 1.f : 0.f;
        m.y = (p.y == rmp && p.y == cp1 && p.y > THR) ? 1.f : 0.f;
        m.z = (p.z == rmp && p.z == cp2 && p.z > THR) ? 1.f : 0.f;
        m.w = (p.w == rmp && p.w == cp3 && p.w > THR) ? 1.f : 0.f;
        ((float4*)maskOut)[idx] = m;
        int cand = 0x7fffffff;
        if (p.w == rmp) cand = col4 + 3;
        if (p.z == rmp) cand = col4 + 2;
        if (p.y == rmp) cand = col4 + 1;
        if (p.x == rmp) cand = col4 + 0;
        candLds[lr * 65 + lane] = cand;
    }
    __syncthreads();
    {
        int row = tid & 63, q = tid >> 6;
        int m = 0x7fffffff;
#pragma unroll
        for (int i = 0; i < 16; ++i) m = min(m, candLds[row * 65 + q * 16 + i]);
        qredi[row * 4 + q] = m;
    }
    __syncthreads();
    if (tid < 64) {
        int m = min(min(qredi[tid * 4 + 0], qredi[tid * 4 + 1]),
                    min(qredi[tid * 4 + 2], qredi[tid * 4 + 3]));
        atomicMin(&argJ[r0 + tid], m);
    }
}

// pass C: valid flag + matched keypoints (tiny)
__global__ __launch_bounds__(256) void valid_kernel(const float* __restrict__ P,
                                                    const unsigned* __restrict__ cmp_rep,
                                                    const int* __restrict__ argJ,
                                                    const float* __restrict__ kpB,
                                                    float* __restrict__ validOut,
                                                    float* __restrict__ matchOut) {
    int n = blockIdx.x * 256 + threadIdx.x;
    int j = argJ[n];
    float pj = P[(size_t)n * NPT + j];
    bool v = (pj == funrep(cmp_rep[j])) && (pj > THR);
    validOut[n] = v ? 1.f : 0.f;
    matchOut[2 * n + 0] = kpB[2 * j + 0];
    matchOut[2 * n + 1] = kpB[2 * j + 1];
}

extern "C" void kernel_launch(void* const* d_in, const int* in_sizes, int n_in,
                              void* d_out, int out_size, void* d_ws, size_t ws_size,
                              hipStream_t stream) {
    const float* dA     = (const float*)d_in[1];  // descriptions_A [4096,256]
    const float* kpB    = (const float*)d_in[2];  // keypoints_B    [4096,2]
    const float* dB     = (const float*)d_in[3];  // descriptions_B [4096,256]
    const float* protos = (const float*)d_in[4];  // prototype_mats [8,256,256]

    float* P      = (float*)d_out;                  // 4096*4096
    float* maskO  = P + (size_t)NPT * NPT;          // 4096*4096
    float* validO = maskO + (size_t)NPT * NPT;      // 4096
    float* matchO = validO + NPT;                   // 4096*2

    // bf16 hi/lo buffers + softmax partials parked in the mask region
    // (mask written only by maskarg at the very end): ~46 MB < 64 MB
    u16* Ahi = (u16*)maskO;                         // 9*4096*256
    u16* Alo = Ahi + (size_t)NVAR * NPT * DIM;
    u16* Bhi = Alo + (size_t)NVAR * NPT * DIM;      // 4096*256
    u16* Blo = Bhi + (size_t)NPT * DIM;
    u16* Phi = Blo + (size_t)NPT * DIM;             // 8*256*256
    u16* Plo = Phi + (size_t)8 * DIM * DIM;
    float* pMaxR = (float*)(Plo + (size_t)8 * DIM * DIM);  // [32][4096]
    float* pSumR = pMaxR + 32 * NPT;
    float* pMaxC = pSumR + 32 * NPT;
    float* pSumC = pMaxC + 32 * NPT;

    // small stats live in ws (~300 KB)
    float* ws      = (float*)d_ws;
    float* a2      = ws;                 // 9*4096
    float* b2      = a2 + NVAR * NPT;    // 4096
    unsigned* rm   = (unsigned*)(b2 + NPT);   // atomic-max targets, contiguous x4
    unsigned* cm   = rm + NPT;
    unsigned* rmp  = cm + NPT;
    unsigned* cmp  = rmp + NPT;
    float* rs      = (float*)(cmp + NPT);
    float* cs      = rs + NPT;
    int* argJ      = (int*)(cs + NPT);

    // zero the four atomic-max arrays; argJ to big sentinel (0x7f7f7f7f)
    hipMemsetAsync(rm, 0, 4 * NPT * sizeof(unsigned), stream);
    hipMemsetAsync(argJ, 0x7f, NPT * sizeof(int), stream);

    conv3_kernel<<<2560, 256, 0, stream>>>(dA, dB, protos, Ahi, Alo, Bhi, Blo, Phi, Plo);
    steer_mfma_kernel<<<dim3(32, 2, 8), 256, 0, stream>>>(Ahi, Alo, Phi, Plo, Ahi, Alo);
    rownorm10_kernel<<<(NVAR + 1) * NPT / 4, 256, 0, stream>>>(Ahi, Alo, Bhi, Blo, a2);
    corr_mfma_kernel<<<dim3(32, 32), 256, 0, stream>>>(Ahi, Alo, Bhi, Blo, a2, b2, P, rm, cm,
                                                       pMaxR, pSumR, pMaxC, pSumC);
    combine_kernel<<<32, 256, 0, stream>>>(rm, cm, pMaxR, pSumR, pMaxC, pSumC, rs, cs);
    pmax_kernel<<<1024, 256, 0, stream>>>(P, rm, cm, rs, cs, rmp, cmp);
    maskarg_kernel<<<1024, 256, 0, stream>>>(P, rmp, cmp, maskO, argJ);
    valid_kernel<<<16, 256, 0, stream>>>(P, cmp, argJ, kpB, validO, matchO);
}